// Round 13
// baseline (142.877 us; speedup 1.0000x reference)
//
#include <hip/hip_runtime.h>
#include <hip/hip_bf16.h>

// Problem constants
#define N_Q   2048
#define M_KV  2048
#define DIM   1024
#define NH    16
#define DHEAD 64
#define KDIM  1024
#define PEROWS 2112   // pe_rel rows actually used: global rows 1984..4094 -> local 0..2111
#define PEBUF  2176

typedef __attribute__((ext_vector_type(8))) __bf16 bf16x8;
typedef __attribute__((ext_vector_type(4))) float  f32x4;

typedef __attribute__((address_space(1))) const unsigned char gbyte_t;
typedef __attribute__((address_space(3))) unsigned char lbyte_t;

__device__ __forceinline__ unsigned short f2bf(float f) {
  union { float f; unsigned u; } v; v.f = f;
  unsigned u = v.u;
  u = u + 0x7fffu + ((u >> 16) & 1u);   // RNE
  return (unsigned short)(u >> 16);
}

// ---------- single fused prep kernel ----------
#define PREP_A 524288
#define PREP_B 1048576
#define PREP_C 2097152
#define PREP_D 2359296
#define PREP_E 2916352
__global__ __launch_bounds__(256) void prep_kernel(
    const float* __restrict__ x_q, const float* __restrict__ x_kv,
    const float* __restrict__ to_q, const float* __restrict__ to_k,
    const float* __restrict__ to_v, const float* __restrict__ to_pe,
    const float* __restrict__ to_out,
    unsigned short* __restrict__ xq_bf, unsigned short* __restrict__ xkv_bf,
    unsigned short* __restrict__ wq_bf, unsigned short* __restrict__ wkv_bf,
    unsigned short* __restrict__ wp_bf, unsigned short* __restrict__ wo_bf,
    unsigned short* __restrict__ sc_bf) {
  int gid = blockIdx.x * 256 + threadIdx.x;
  if (gid < PREP_B) {            // cvt x_q / x_kv, float4 -> 4x bf16
    const float* src = (gid < PREP_A) ? x_q : x_kv;
    unsigned short* dst = (gid < PREP_A) ? xq_bf : xkv_bf;
    int e4 = (gid < PREP_A ? gid : gid - PREP_A) * 4;
    float4 v = *(const float4*)(src + e4);
    ushort4 o = { f2bf(v.x), f2bf(v.y), f2bf(v.z), f2bf(v.w) };
    *(ushort4*)(dst + e4) = o;
  } else if (gid < PREP_C) {     // pack4: (DHEAD,NH,DIM) -> (h*64+d, DIM)
    int e = gid - PREP_B;
    int which = e >> 18, inner = e & 262143;
    int e4 = inner * 4;
    int j = e4 >> 10, b = e4 & 1023;
    int d = j & 63, h = j >> 6;
    const float* w = (which == 0) ? to_q : (which == 1) ? to_k : (which == 2) ? to_v : to_pe;
    unsigned short* o = (which == 0) ? wq_bf : (which == 1) ? wkv_bf
                       : (which == 2) ? (wkv_bf + (size_t)DIM * DIM) : wp_bf;
    float4 v = *(const float4*)(w + (size_t)(d * NH + h) * DIM + b);
    ushort4 u = { f2bf(v.x), f2bf(v.y), f2bf(v.z), f2bf(v.w) };
    *(ushort4*)(o + e4) = u;
  } else if (gid < PREP_D) {     // pack_wo: (DIM,DHEAD,NH) -> (DIM, h*64+c)
    int e4 = (gid - PREP_C) * 4;
    int dd = e4 >> 10, jc = e4 & 1023;
    int c = jc & 63, h = jc >> 6;
    const float* base = to_out + (size_t)(dd * DHEAD + c) * NH + h;
    ushort4 u = { f2bf(base[0]), f2bf(base[16]), f2bf(base[32]), f2bf(base[48]) };
    *(ushort4*)(wo_bf + e4) = u;
  } else if (gid < PREP_E) {     // sincos: row r, 2 k2-cols per thread
    int e = gid - PREP_D;
    int r = e >> 8, t8 = e & 255;
    float ph0base = (float)(r - 63);
    unsigned short ss[2], cc[2];
    #pragma unroll
    for (int i = 0; i < 2; ++i) {
      int k2 = t8 * 2 + i;
      float invf = __expf((float)k2 * (-9.210340371976184f / 512.0f));  // 10000^(-k2/512)
      float s, c;
      __sincosf(ph0base * invf, &s, &c);
      ss[i] = f2bf(s); cc[i] = f2bf(c);
    }
    unsigned short* row = sc_bf + (size_t)r * DIM;
    *(unsigned int*)(row + t8 * 2)       = (unsigned)ss[0] | ((unsigned)ss[1] << 16);
    *(unsigned int*)(row + t8 * 2 + 512) = (unsigned)cc[0] | ((unsigned)cc[1] << 16);
  }
}

// ---------- fused input GEMMs, 128x64 tiles, 1040 blocks, XCD-chunked ----------
// 3-deep LDS ring + counted vmcnt (T4): iter t issues stage(t+2), computes buf t,
// then s_waitcnt vmcnt(6) [stage(t+1) retired, stage(t+2) still in flight] +
// raw s_barrier. Staging loads get ~2 K-steps of latency cover; never drained to 0.
__global__ __launch_bounds__(256) void gemm_in_kernel(
    const unsigned short* __restrict__ xq, const unsigned short* __restrict__ xkv,
    const unsigned short* __restrict__ sc,
    const unsigned short* __restrict__ wq, const unsigned short* __restrict__ wkv,
    const unsigned short* __restrict__ wp,
    unsigned short* __restrict__ qout, unsigned short* __restrict__ kout,
    unsigned short* __restrict__ vtout, unsigned short* __restrict__ peout) {
  int bid0 = (int)blockIdx.x;
  int bid  = (bid0 & 7) * 130 + (bid0 >> 3);   // bijective: 1040 = 8 * 130
  const unsigned short *A, *B; unsigned short *C1, *C2;
  int Mr, maxBrow, mode, ax, by;
  if (bid < 256)      { int t = bid;       ax = t & 15; by = t >> 4; A = xq;  B = wq;  C1 = qout;  C2 = nullptr; Mr = N_Q;    maxBrow = DIM - 1;     mode = 1; }
  else if (bid < 768) { int t = bid - 256; ax = t & 15; by = t >> 4; A = xkv; B = wkv; C1 = kout;  C2 = vtout;   Mr = M_KV;   maxBrow = 2 * DIM - 1; mode = 3; }
  else                { int t = bid - 768; ax = t % 17; by = t / 17; A = sc;  B = wp;  C1 = peout; C2 = nullptr; Mr = PEROWS; maxBrow = DIM - 1;     mode = 1; }

  __shared__ unsigned short As[3][128][64];   // 48 KB
  __shared__ unsigned short Bs[3][64][64];    // 24 KB
  int tid  = threadIdx.x;
  int wave = tid >> 6, lane = tid & 63;
  int g = lane >> 4, r16 = lane & 15;
  int arow0 = ax * 128;
  int brow0 = by * 64;
  int amax  = Mr - 1;

  // 6 global_load_lds per wave per stage (4 A + 2 B)
  auto stage = [&](int buf, int kt) {
    #pragma unroll
    for (int n = 0; n < 4; ++n) {
      int seg  = wave * 4 + n;
      int rloc = seg * 8 + (lane >> 3);
      int cbyte = ((lane & 7) << 4) ^ ((rloc & 7) << 4);
      int grow = min(arow0 + rloc, amax);
      const unsigned short* gp = A + (size_t)grow * KDIM + kt + (cbyte >> 1);
      __builtin_amdgcn_global_load_lds((gbyte_t*)(const void*)gp,
                                       (lbyte_t*)(void*)&As[buf][seg * 8][0], 16, 0, 0);
    }
    #pragma unroll
    for (int n = 0; n < 2; ++n) {
      int seg  = wave * 2 + n;
      int rloc = seg * 8 + (lane >> 3);
      int cbyte = ((lane & 7) << 4) ^ ((rloc & 7) << 4);
      int grow = min(brow0 + rloc, maxBrow);
      const unsigned short* gp = B + (size_t)grow * KDIM + kt + (cbyte >> 1);
      __builtin_amdgcn_global_load_lds((gbyte_t*)(const void*)gp,
                                       (lbyte_t*)(void*)&Bs[buf][seg * 8][0], 16, 0, 0);
    }
  };

  f32x4 acc[2][4];
  #pragma unroll
  for (int i = 0; i < 2; ++i)
    #pragma unroll
    for (int j = 0; j < 4; ++j) acc[i][j] = (f32x4){0,0,0,0};

  stage(0, 0);
  stage(1, 64);
  asm volatile("s_waitcnt vmcnt(6)" ::: "memory");   // stage(0) retired
  __builtin_amdgcn_s_barrier();
  __builtin_amdgcn_sched_barrier(0);

  int bcur = 0;
  for (int t = 0; t < 16; ++t) {
    if (t + 2 < 16) {
      int bstage = bcur + 2; if (bstage >= 3) bstage -= 3;
      stage(bstage, (t + 2) * 64);
    }

    bf16x8 af[2][2], bfr[4][2];
    #pragma unroll
    for (int i = 0; i < 2; ++i)
      #pragma unroll
      for (int kk = 0; kk < 2; ++kk) {
        int r = wave * 32 + i * 16 + r16;
        int cb = ((kk << 6) | (g << 4)) ^ ((r & 7) << 4);
        af[i][kk] = *(const bf16x8*)((const char*)&As[bcur][r][0] + cb);
      }
    #pragma unroll
    for (int j = 0; j < 4; ++j)
      #pragma unroll
      for (int kk = 0; kk < 2; ++kk) {
        int r = j * 16 + r16;
        int cb = ((kk << 6) | (g << 4)) ^ ((r & 7) << 4);
        bfr[j][kk] = *(const bf16x8*)((const char*)&Bs[bcur][r][0] + cb);
      }
    __builtin_amdgcn_s_setprio(1);
    #pragma unroll
    for (int kk = 0; kk < 2; ++kk)
      #pragma unroll
      for (int i = 0; i < 2; ++i)
        #pragma unroll
        for (int j = 0; j < 4; ++j)
          acc[i][j] = __builtin_amdgcn_mfma_f32_16x16x32_bf16(af[i][kk], bfr[j][kk], acc[i][j], 0, 0, 0);
    __builtin_amdgcn_s_setprio(0);

    if (t + 1 < 16) {
      if (t + 2 < 16) asm volatile("s_waitcnt vmcnt(6)" ::: "memory");  // stage(t+1) retired
      else            asm volatile("s_waitcnt vmcnt(0)" ::: "memory");  // tail
      __builtin_amdgcn_s_barrier();
      __builtin_amdgcn_sched_barrier(0);
      bcur = (bcur == 2) ? 0 : bcur + 1;
    }
  }

  #pragma unroll
  for (int i = 0; i < 2; ++i)
    #pragma unroll
    for (int j = 0; j < 4; ++j)
      #pragma unroll
      for (int rr = 0; rr < 4; ++rr) {
        int row = arow0 + wave * 32 + i * 16 + g * 4 + rr;
        int col = brow0 + j * 16 + r16;
        float v = acc[i][j][rr];
        if (mode == 1) {
          if (row < Mr) C1[(size_t)row * 1024 + col] = f2bf(v);
        } else {
          if (col < 1024) C1[(size_t)row * 1024 + col] = f2bf(v);
          else            C2[(size_t)(col - 1024) * M_KV + row] = f2bf(v);
        }
      }
}

// ---------- output projection GEMM: 64x64 tiles, 3-buf counted-vmcnt, f32 out ----------
__global__ __launch_bounds__(256) void gemm_out_kernel(
    const unsigned short* __restrict__ A, const unsigned short* __restrict__ B,
    float* __restrict__ C1) {
  __shared__ unsigned short As[3][64][64];   // 24 KB
  __shared__ unsigned short Bs[3][64][64];   // 24 KB
  int tid  = threadIdx.x;
  int wave = tid >> 6, lane = tid & 63;
  int wr = wave >> 1, wc = wave & 1;
  int g = lane >> 4, r16 = lane & 15;
  int arow0 = blockIdx.x * 64;
  int brow0 = blockIdx.y * 64;

  // 4 loads per wave per stage (2 A + 2 B)
  auto stage = [&](int buf, int kt) {
    #pragma unroll
    for (int n = 0; n < 2; ++n) {
      int seg  = wave * 2 + n;
      int rloc = seg * 8 + (lane >> 3);
      int cbyte = ((lane & 7) << 4) ^ ((rloc & 7) << 4);
      const unsigned short* gpA = A + (size_t)(arow0 + rloc) * KDIM + kt + (cbyte >> 1);
      __builtin_amdgcn_global_load_lds((gbyte_t*)(const void*)gpA,
                                       (lbyte_t*)(void*)&As[buf][seg * 8][0], 16, 0, 0);
      const unsigned short* gpB = B + (size_t)(brow0 + rloc) * KDIM + kt + (cbyte >> 1);
      __builtin_amdgcn_global_load_lds((gbyte_t*)(const void*)gpB,
                                       (lbyte_t*)(void*)&Bs[buf][seg * 8][0], 16, 0, 0);
    }
  };

  f32x4 acc[2][2] = {{{0,0,0,0},{0,0,0,0}},{{0,0,0,0},{0,0,0,0}}};

  stage(0, 0);
  stage(1, 64);
  asm volatile("s_waitcnt vmcnt(4)" ::: "memory");
  __builtin_amdgcn_s_barrier();
  __builtin_amdgcn_sched_barrier(0);

  int bcur = 0;
  for (int t = 0; t < 16; ++t) {
    if (t + 2 < 16) {
      int bstage = bcur + 2; if (bstage >= 3) bstage -= 3;
      stage(bstage, (t + 2) * 64);
    }
    bf16x8 af[2][2], bfr[2][2];
    #pragma unroll
    for (int i = 0; i < 2; ++i)
      #pragma unroll
      for (int kk = 0; kk < 2; ++kk) {
        int r = wr * 32 + i * 16 + r16;
        int cb = ((kk << 6) | (g << 4)) ^ ((r & 7) << 4);
        af[i][kk] = *(const bf16x8*)((const char*)&As[bcur][r][0] + cb);
      }
    #pragma unroll
    for (int j = 0; j < 2; ++j)
      #pragma unroll
      for (int kk = 0; kk < 2; ++kk) {
        int r = wc * 32 + j * 16 + r16;
        int cb = ((kk << 6) | (g << 4)) ^ ((r & 7) << 4);
        bfr[j][kk] = *(const bf16x8*)((const char*)&Bs[bcur][r][0] + cb);
      }
    __builtin_amdgcn_s_setprio(1);
    #pragma unroll
    for (int kk = 0; kk < 2; ++kk)
      #pragma unroll
      for (int i = 0; i < 2; ++i)
        #pragma unroll
        for (int j = 0; j < 2; ++j)
          acc[i][j] = __builtin_amdgcn_mfma_f32_16x16x32_bf16(af[i][kk], bfr[j][kk], acc[i][j], 0, 0, 0);
    __builtin_amdgcn_s_setprio(0);
    if (t + 1 < 16) {
      if (t + 2 < 16) asm volatile("s_waitcnt vmcnt(4)" ::: "memory");
      else            asm volatile("s_waitcnt vmcnt(0)" ::: "memory");
      __builtin_amdgcn_s_barrier();
      __builtin_amdgcn_sched_barrier(0);
      bcur = (bcur == 2) ? 0 : bcur + 1;
    }
  }

  #pragma unroll
  for (int i = 0; i < 2; ++i)
    #pragma unroll
    for (int j = 0; j < 2; ++j)
      #pragma unroll
      for (int rr = 0; rr < 4; ++rr) {
        int row = arow0 + wr * 32 + i * 16 + g * 4 + rr;
        int col = brow0 + wc * 32 + j * 16 + r16;
        C1[(size_t)row * 1024 + col] = acc[i][j][rr];
      }
}

// ---------- fused causal attention, MFMA, split-KV, LDS-pipelined (R9 structure) ----------
__global__ __launch_bounds__(256, 2) void attn_mfma_kernel(
    const unsigned short* __restrict__ qb, const unsigned short* __restrict__ kb,
    const unsigned short* __restrict__ vt, const unsigned short* __restrict__ pe,
    unsigned short* __restrict__ ctx, float* __restrict__ part) {
  int ord  = (int)blockIdx.x;
  int h    = ord & 15;
  int widx = 79 - (ord >> 4);               // heavy chunks dispatched first
  int b, c;
  if (widx < 8)       { b = widx;                                  c = 0; }
  else if (widx < 24) { int t2 = widx - 8;  b = 8  + (t2 >> 1);    c = t2 & 1; }
  else if (widx < 48) { int t2 = widx - 24; int q3 = t2 / 3; b = 16 + q3; c = t2 - 3 * q3; }
  else                { int t2 = widx - 48; b = 24 + (t2 >> 2);    c = t2 & 3; }
  int n0   = b * 64;
  int nc   = (b < 8) ? 1 : (b >> 3) + 1;
  int t0   = c * 8;
  int tend = min(t0 + 8, b + 1);

  int wave = threadIdx.x >> 6;
  int lane = threadIdx.x & 63;
  int g    = lane >> 4;       // 0..3
  int r16  = lane & 15;       // 0..15

  __shared__ unsigned short Ks[2][64][64];     // 16 KB  k tile   [j-local][d]
  __shared__ unsigned short Vs[2][64][64];     // 16 KB  v tile   [d-local][j-local]
  __shared__ unsigned short PEs[2][128][64];   // 32 KB  pe band  [band-local][d]
  __shared__ unsigned short W_lds[4][16][72];  // 9.2 KB per-wave W

  const unsigned short* qrow = qb + (size_t)(n0 + wave * 16 + r16) * DIM + h * 64 + g * 8;
  bf16x8 aq0 = *(const bf16x8*)(qrow);
  bf16x8 aq1 = *(const bf16x8*)(qrow + 32);

  union { unsigned short u[8]; bf16x8 v; } one_u;
  #pragma unroll
  for (int i = 0; i < 8; ++i) one_u.u[i] = 0x3F80;   // bf16 1.0
  bf16x8 ones = one_u.v;

  f32x4 acc[4] = {{0,0,0,0},{0,0,0,0},{0,0,0,0},{0,0,0,0}};
  f32x4 lacc = {0,0,0,0};

  auto stage = [&](int bufn, int tilen) {
    int m0n = tilen * 64;
    int prb = n0 - m0n;
    #pragma unroll
    for (int n = 0; n < 2; ++n) {
      int seg  = wave * 2 + n;
      int rloc = seg * 8 + (lane >> 3);
      int cbyte = ((lane & 7) << 4) ^ ((rloc & 7) << 4);
      const unsigned short* gpk = kb + (size_t)(m0n + rloc) * KDIM + h * 64 + (cbyte >> 1);
      __builtin_amdgcn_global_load_lds((gbyte_t*)(const void*)gpk,
                                       (lbyte_t*)(void*)&Ks[bufn][seg * 8][0], 16, 0, 0);
      const unsigned short* gpv = vt + (size_t)(h * 64 + rloc) * M_KV + m0n + (cbyte >> 1);
      __builtin_amdgcn_global_load_lds((gbyte_t*)(const void*)gpv,
                                       (lbyte_t*)(void*)&Vs[bufn][seg * 8][0], 16, 0, 0);
    }
    #pragma unroll
    for (int n = 0; n < 4; ++n) {
      int seg  = wave * 4 + n;
      int rloc = seg * 8 + (lane >> 3);
      int cbyte = ((lane & 7) << 4) ^ ((rloc & 7) << 4);
      const unsigned short* gpp = pe + (size_t)(prb + rloc) * KDIM + h * 64 + (cbyte >> 1);
      __builtin_amdgcn_global_load_lds((gbyte_t*)(const void*)gpp,
                                       (lbyte_t*)(void*)&PEs[bufn][seg * 8][0], 16, 0, 0);
    }
  };

  int srcl[4]; bool hi_sel[4];
  #pragma unroll
  for (int rr = 0; rr < 4; ++rr) {
    srcl[rr]   = (g << 4) | ((g * 4 + rr + 63 - r16) & 15);
    hi_sel[rr] = (g * 4 + rr) > r16;
  }
  int sw = (r16 & 7) << 4;                     // read-side swizzle

  stage(0, t0);
  asm volatile("s_waitcnt vmcnt(0)" ::: "memory");
  __syncthreads();

  int buf = 0;
  for (int tile = t0; tile < tend; ++tile) {
    int m0 = tile * 64;
    if (tile + 1 < tend) stage(buf ^ 1, tile + 1);

    // ---- content S strip (16 x 64): 8 ds_read_b128 + 8 MFMA ----
    f32x4 s[4];
    __builtin_amdgcn_s_setprio(1);
    #pragma unroll
    for (int ct = 0; ct < 4; ++ct) {
      const char* kbase = (const char*)&Ks[buf][ct * 16 + r16][0];
      bf16x8 k0 = *(const bf16x8*)(kbase + (((g << 4)) ^ sw));
      bf16x8 k1 = *(const bf16x8*)(kbase + ((64 | (g << 4)) ^ sw));
      f32x4 z = {0,0,0,0};
      z = __builtin_amdgcn_mfma_f32_16x16x32_bf16(aq0, k0, z, 0, 0, 0);
      z = __builtin_amdgcn_mfma_f32_16x16x32_bf16(aq1, k1, z, 0, 0, 0);
      s[ct] = z;
    }

    // ---- position P^T: 10 reads + 10 MFMA ----
    f32x4 z2[5];
    #pragma unroll
    for (int cp = 0; cp < 5; ++cp) {
      const char* pbase = (const char*)&PEs[buf][wave * 16 + cp * 16 + r16][0];
      bf16x8 p0 = *(const bf16x8*)(pbase + (((g << 4)) ^ sw));
      bf16x8 p1 = *(const bf16x8*)(pbase + ((64 | (g << 4)) ^ sw));
      f32x4 z = {0,0,0,0};
      z = __builtin_amdgcn_mfma_f32_16x16x32_bf16(aq0, p0, z, 0, 0, 0);
      z = __builtin_amdgcn_mfma_f32_16x16x32_bf16(aq1, p1, z, 0, 0, 0);
      z2[cp] = z;
    }
    __builtin_amdgcn_s_setprio(0);

    // ---- in-register band gather + causal mask + exp ----
    bool diag = (m0 == n0);
    #pragma unroll
    for (int ct = 0; ct < 4; ++ct) {
      #pragma unroll
      for (int rr = 0; rr < 4; ++rr) {
        float vhi = __shfl(z2[4 - ct][rr], srcl[rr], 64);
        float vlo = __shfl(z2[3 - ct][rr], srcl[rr], 64);
        float p   = hi_sel[rr] ? vhi : vlo;
        int il = g * 4 + rr;
        int it = wave * 16 + il;
        int jt = ct * 16 + r16;
        float val = s[ct][rr] + p;
        if (diag && jt > it) val = -1e30f;
        s[ct][rr] = __expf(val);
      }
    }

    // ---- W (bf16) to LDS, reread as PV A-fragments ----
    #pragma unroll
    for (int ct = 0; ct < 4; ++ct)
      #pragma unroll
      for (int rr = 0; rr < 4; ++rr)
        W_lds[wave][g * 4 + rr][ct * 16 + r16] = f2bf(s[ct][rr]);
    bf16x8 aw0 = *(const bf16x8*)(&W_lds[wave][r16][g * 8]);
    bf16x8 aw1 = *(const bf16x8*)(&W_lds[wave][r16][g * 8 + 32]);

    // ---- PV: 8 ds_read_b128 + 10 MFMA ----
    __builtin_amdgcn_s_setprio(1);
    #pragma unroll
    for (int ct = 0; ct < 4; ++ct) {
      const char* vbase = (const char*)&Vs[buf][ct * 16 + r16][0];
      bf16x8 v0 = *(const bf16x8*)(vbase + (((g << 4)) ^ sw));
      bf16x8 v1 = *(const bf16x8*)(vbase + ((64 | (g << 4)) ^ sw));
      f32x4 a = acc[ct];
      a = __builtin_amdgcn_mfma_f32_16x16x32_bf16(aw0, v0, a, 0, 0, 0);
      a = __builtin_amdgcn_mfma_f32_16x16x32_bf16(aw1, v1, a, 0, 0, 0);
      acc[ct] = a;
    }
    lacc = __builtin_amdgcn_mfma_f32_16x16x32_bf16(aw0, ones, lacc, 0, 0, 0);
    lacc = __builtin_amdgcn_mfma_f32_16x16x32_bf16(aw1, ones, lacc, 0, 0, 0);
    __builtin_amdgcn_s_setprio(0);

    asm volatile("s_waitcnt vmcnt(0)" ::: "memory");
    __syncthreads();
    buf ^= 1;
  }

  // ---- epilogue ----
  if (nc == 1) {
    #pragma unroll
    for (int rr = 0; rr < 4; ++rr) {
      float inv = 1.0f / lacc[rr];
      #pragma unroll
      for (int ct = 0; ct < 4; ++ct) {
        int row = n0 + wave * 16 + g * 4 + rr;
        ctx[(size_t)row * DIM + h * 64 + ct * 16 + r16] = f2bf(acc[ct][rr] * inv);
      }
    }
  } else {
    float* slot = part + ((size_t)((b - 8) * 16 + h) * 4 + c) * (64 * 68);
    #pragma unroll
    for (int ct = 0; ct < 4; ++ct)
      #pragma unroll
      for (int rr = 0; rr < 4; ++rr) {
        int row = wave * 16 + g * 4 + rr;
        slot[row * 68 + ct * 16 + r16] = acc[ct][rr];
      }
    if (r16 == 0) {
      #pragma unroll
      for (int rr = 0; rr < 4; ++rr) {
        int row = wave * 16 + g * 4 + rr;
        slot[row * 68 + 64] = lacc[rr];
      }
    }
  }
}

// ---------- merge split-KV partials (q-tiles b>=8) ----------
__global__ __launch_bounds__(256) void combine_kernel(const float* __restrict__ part,
                                                      unsigned short* __restrict__ ctx) {
  int bb = blockIdx.x;       // 0..23 -> b = bb+8
  int h  = blockIdx.y;
  int b  = bb + 8;
  int nc = (b >> 3) + 1;     // 2..4
  int t  = threadIdx.x;
  int row = t >> 2, q = t & 3;
  const float* base = part + ((size_t)(bb * 16 + h) * 4) * (64 * 68) + row * 68;
  float lstar = 0.0f;
  for (int c2 = 0; c2 < nc; ++c2) lstar += base[c2 * 4352 + 64];
  float inv = 1.0f / lstar;
  for (int cc = 0; cc < 16; ++cc) {
    int col = q * 16 + cc;
    float o = 0.0f;
    for (int c2 = 0; c2 < nc; ++c2) o += base[c2 * 4352 + col];
    ctx[(size_t)(b * 64 + row) * DIM + h * 64 + col] = f2bf(o * inv);
  }
}

extern "C" void kernel_launch(void* const* d_in, const int* in_sizes, int n_in,
                              void* d_out, int out_size, void* d_ws, size_t ws_size,
                              hipStream_t stream) {
  const float* x_q    = (const float*)d_in[0];
  const float* x_kv   = (const float*)d_in[1];
  const float* to_q   = (const float*)d_in[2];
  const float* to_k   = (const float*)d_in[3];
  const float* to_v   = (const float*)d_in[4];
  const float* to_out = (const float*)d_in[5];
  const float* to_pe  = (const float*)d_in[6];

  char* ws = (char*)d_ws;
  size_t off = 0;
  auto alloc = [&](size_t bytes) -> char* {
    char* p = ws + off;
    off += (bytes + 255) & ~(size_t)255;
    return p;
  };

  unsigned short* xq_bf  = (unsigned short*)alloc((size_t)N_Q  * DIM * 2);
  unsigned short* xkv_bf = (unsigned short*)alloc((size_t)M_KV * DIM * 2);
  unsigned short* wq_bf  = (unsigned short*)alloc((size_t)DIM * DIM * 2);
  unsigned short* wkv_bf = (unsigned short*)alloc((size_t)2 * DIM * DIM * 2);  // [wk; wv]
  unsigned short* wp_bf  = (unsigned short*)alloc((size_t)DIM * DIM * 2);
  unsigned short* wo_bf  = (unsigned short*)alloc((size_t)DIM * DIM * 2);
  unsigned short* sc_bf  = (unsigned short*)alloc((size_t)PEBUF * DIM * 2);
  unsigned short* q_bf   = (unsigned short*)alloc((size_t)N_Q  * DIM * 2);
  unsigned short* k_bf   = (unsigned short*)alloc((size_t)M_KV * DIM * 2);
  unsigned short* vt_bf  = (unsigned short*)alloc((size_t)DIM * M_KV * 2);
  unsigned short* pe_bf  = (unsigned short*)alloc((size_t)PEBUF * DIM * 2);
  unsigned short* ctx_bf = (unsigned short*)alloc((size_t)N_Q * DIM * 2);
  float*          part   = (float*)alloc((size_t)24 * 16 * 4 * 64 * 68 * 4);

  // fused prep (cvt + packs + sincos)
  prep_kernel<<<11392, 256, 0, stream>>>(x_q, x_kv, to_q, to_k, to_v, to_pe, to_out,
                                         xq_bf, xkv_bf, wq_bf, wkv_bf, wp_bf, wo_bf, sc_bf);

  // fused input projections (q, k|vt, pe), 128x64 tiles, XCD-chunked, 3-buf counted-vmcnt
  gemm_in_kernel<<<1040, 256, 0, stream>>>(xq_bf, xkv_bf, sc_bf, wq_bf, wkv_bf, wp_bf,
                                           q_bf, k_bf, vt_bf, pe_bf);

  // fused attention (split-KV, LDS 2-phase pipeline) + combine
  attn_mfma_kernel<<<1280, 256, 0, stream>>>(q_bf, k_bf, vt_bf, pe_bf, ctx_bf, part);
  combine_kernel<<<dim3(24, NH), 256, 0, stream>>>(part, ctx_bf);

  // output projection -> d_out (f32)
  gemm_out_kernel<<<dim3(32, 16), 256, 0, stream>>>(ctx_bf, wo_bf, (float*)d_out);
}

// Round 14
// 136.774 us; speedup vs baseline: 1.0446x; 1.0446x over previous
//
#include <hip/hip_runtime.h>
#include <hip/hip_bf16.h>

// Problem constants
#define N_Q   2048
#define M_KV  2048
#define DIM   1024
#define NH    16
#define DHEAD 64
#define KDIM  1024
#define PEROWS 2112   // pe_rel rows actually used: global rows 1984..4094 -> local 0..2111
#define PEBUF  2176

typedef __attribute__((ext_vector_type(8))) __bf16 bf16x8;
typedef __attribute__((ext_vector_type(4))) float  f32x4;

typedef __attribute__((address_space(1))) const unsigned char gbyte_t;
typedef __attribute__((address_space(3))) unsigned char lbyte_t;

__device__ __forceinline__ unsigned short f2bf(float f) {
  union { float f; unsigned u; } v; v.f = f;
  unsigned u = v.u;
  u = u + 0x7fffu + ((u >> 16) & 1u);   // RNE
  return (unsigned short)(u >> 16);
}

// ---------- single fused prep kernel ----------
#define PREP_A 524288
#define PREP_B 1048576
#define PREP_C 2097152
#define PREP_D 2359296
#define PREP_E 2916352
__global__ __launch_bounds__(256) void prep_kernel(
    const float* __restrict__ x_q, const float* __restrict__ x_kv,
    const float* __restrict__ to_q, const float* __restrict__ to_k,
    const float* __restrict__ to_v, const float* __restrict__ to_pe,
    const float* __restrict__ to_out,
    unsigned short* __restrict__ xq_bf, unsigned short* __restrict__ xkv_bf,
    unsigned short* __restrict__ wq_bf, unsigned short* __restrict__ wkv_bf,
    unsigned short* __restrict__ wp_bf, unsigned short* __restrict__ wo_bf,
    unsigned short* __restrict__ sc_bf) {
  int gid = blockIdx.x * 256 + threadIdx.x;
  if (gid < PREP_B) {            // cvt x_q / x_kv, float4 -> 4x bf16
    const float* src = (gid < PREP_A) ? x_q : x_kv;
    unsigned short* dst = (gid < PREP_A) ? xq_bf : xkv_bf;
    int e4 = (gid < PREP_A ? gid : gid - PREP_A) * 4;
    float4 v = *(const float4*)(src + e4);
    ushort4 o = { f2bf(v.x), f2bf(v.y), f2bf(v.z), f2bf(v.w) };
    *(ushort4*)(dst + e4) = o;
  } else if (gid < PREP_C) {     // pack4: (DHEAD,NH,DIM) -> (h*64+d, DIM)
    int e = gid - PREP_B;
    int which = e >> 18, inner = e & 262143;
    int e4 = inner * 4;
    int j = e4 >> 10, b = e4 & 1023;
    int d = j & 63, h = j >> 6;
    const float* w = (which == 0) ? to_q : (which == 1) ? to_k : (which == 2) ? to_v : to_pe;
    unsigned short* o = (which == 0) ? wq_bf : (which == 1) ? wkv_bf
                       : (which == 2) ? (wkv_bf + (size_t)DIM * DIM) : wp_bf;
    float4 v = *(const float4*)(w + (size_t)(d * NH + h) * DIM + b);
    ushort4 u = { f2bf(v.x), f2bf(v.y), f2bf(v.z), f2bf(v.w) };
    *(ushort4*)(o + e4) = u;
  } else if (gid < PREP_D) {     // pack_wo: (DIM,DHEAD,NH) -> (DIM, h*64+c)
    int e4 = (gid - PREP_C) * 4;
    int dd = e4 >> 10, jc = e4 & 1023;
    int c = jc & 63, h = jc >> 6;
    const float* base = to_out + (size_t)(dd * DHEAD + c) * NH + h;
    ushort4 u = { f2bf(base[0]), f2bf(base[16]), f2bf(base[32]), f2bf(base[48]) };
    *(ushort4*)(wo_bf + e4) = u;
  } else if (gid < PREP_E) {     // sincos: row r, 2 k2-cols per thread
    int e = gid - PREP_D;
    int r = e >> 8, t8 = e & 255;
    float ph0base = (float)(r - 63);
    unsigned short ss[2], cc[2];
    #pragma unroll
    for (int i = 0; i < 2; ++i) {
      int k2 = t8 * 2 + i;
      float invf = __expf((float)k2 * (-9.210340371976184f / 512.0f));  // 10000^(-k2/512)
      float s, c;
      __sincosf(ph0base * invf, &s, &c);
      ss[i] = f2bf(s); cc[i] = f2bf(c);
    }
    unsigned short* row = sc_bf + (size_t)r * DIM;
    *(unsigned int*)(row + t8 * 2)       = (unsigned)ss[0] | ((unsigned)ss[1] << 16);
    *(unsigned int*)(row + t8 * 2 + 512) = (unsigned)cc[0] | ((unsigned)cc[1] << 16);
  }
}

// ---------- fused input GEMMs, 128x64 tiles, 1040 blocks, XCD-chunked swizzle ----------
// R12-proven config: 2-buf, 48 KB LDS -> 3 blocks/CU. Occupancy slots beat pipeline depth here.
__global__ __launch_bounds__(256) void gemm_in_kernel(
    const unsigned short* __restrict__ xq, const unsigned short* __restrict__ xkv,
    const unsigned short* __restrict__ sc,
    const unsigned short* __restrict__ wq, const unsigned short* __restrict__ wkv,
    const unsigned short* __restrict__ wp,
    unsigned short* __restrict__ qout, unsigned short* __restrict__ kout,
    unsigned short* __restrict__ vtout, unsigned short* __restrict__ peout) {
  int bid0 = (int)blockIdx.x;
  int bid  = (bid0 & 7) * 130 + (bid0 >> 3);   // bijective: 1040 = 8 * 130
  const unsigned short *A, *B; unsigned short *C1, *C2;
  int Mr, maxBrow, mode, ax, by;
  if (bid < 256)      { int t = bid;       ax = t & 15; by = t >> 4; A = xq;  B = wq;  C1 = qout;  C2 = nullptr; Mr = N_Q;    maxBrow = DIM - 1;     mode = 1; }
  else if (bid < 768) { int t = bid - 256; ax = t & 15; by = t >> 4; A = xkv; B = wkv; C1 = kout;  C2 = vtout;   Mr = M_KV;   maxBrow = 2 * DIM - 1; mode = 3; }
  else                { int t = bid - 768; ax = t % 17; by = t / 17; A = sc;  B = wp;  C1 = peout; C2 = nullptr; Mr = PEROWS; maxBrow = DIM - 1;     mode = 1; }

  __shared__ unsigned short As[2][128][64];
  __shared__ unsigned short Bs[2][64][64];
  int tid  = threadIdx.x;
  int wave = tid >> 6, lane = tid & 63;
  int g = lane >> 4, r16 = lane & 15;
  int arow0 = ax * 128;
  int brow0 = by * 64;
  int amax  = Mr - 1;

  auto stage = [&](int buf, int kt) {
    #pragma unroll
    for (int n = 0; n < 4; ++n) {
      int seg  = wave * 4 + n;
      int rloc = seg * 8 + (lane >> 3);
      int cbyte = ((lane & 7) << 4) ^ ((rloc & 7) << 4);
      int grow = min(arow0 + rloc, amax);
      const unsigned short* gp = A + (size_t)grow * KDIM + kt + (cbyte >> 1);
      __builtin_amdgcn_global_load_lds((gbyte_t*)(const void*)gp,
                                       (lbyte_t*)(void*)&As[buf][seg * 8][0], 16, 0, 0);
    }
    #pragma unroll
    for (int n = 0; n < 2; ++n) {
      int seg  = wave * 2 + n;
      int rloc = seg * 8 + (lane >> 3);
      int cbyte = ((lane & 7) << 4) ^ ((rloc & 7) << 4);
      int grow = min(brow0 + rloc, maxBrow);
      const unsigned short* gp = B + (size_t)grow * KDIM + kt + (cbyte >> 1);
      __builtin_amdgcn_global_load_lds((gbyte_t*)(const void*)gp,
                                       (lbyte_t*)(void*)&Bs[buf][seg * 8][0], 16, 0, 0);
    }
  };

  f32x4 acc[2][4];
  #pragma unroll
  for (int i = 0; i < 2; ++i)
    #pragma unroll
    for (int j = 0; j < 4; ++j) acc[i][j] = (f32x4){0,0,0,0};

  stage(0, 0);
  asm volatile("s_waitcnt vmcnt(0)" ::: "memory");
  __syncthreads();

  int buf = 0;
  for (int t = 0; t < 16; ++t) {
    if (t < 15) stage(buf ^ 1, (t + 1) * 64);

    bf16x8 af[2][2], bfr[4][2];
    #pragma unroll
    for (int i = 0; i < 2; ++i)
      #pragma unroll
      for (int kk = 0; kk < 2; ++kk) {
        int r = wave * 32 + i * 16 + r16;
        int cb = ((kk << 6) | (g << 4)) ^ ((r & 7) << 4);
        af[i][kk] = *(const bf16x8*)((const char*)&As[buf][r][0] + cb);
      }
    #pragma unroll
    for (int j = 0; j < 4; ++j)
      #pragma unroll
      for (int kk = 0; kk < 2; ++kk) {
        int r = j * 16 + r16;
        int cb = ((kk << 6) | (g << 4)) ^ ((r & 7) << 4);
        bfr[j][kk] = *(const bf16x8*)((const char*)&Bs[buf][r][0] + cb);
      }
    __builtin_amdgcn_s_setprio(1);
    #pragma unroll
    for (int kk = 0; kk < 2; ++kk)
      #pragma unroll
      for (int i = 0; i < 2; ++i)
        #pragma unroll
        for (int j = 0; j < 4; ++j)
          acc[i][j] = __builtin_amdgcn_mfma_f32_16x16x32_bf16(af[i][kk], bfr[j][kk], acc[i][j], 0, 0, 0);
    __builtin_amdgcn_s_setprio(0);

    if (t < 15) {
      asm volatile("s_waitcnt vmcnt(0)" ::: "memory");
      __syncthreads();
      buf ^= 1;
    }
  }

  #pragma unroll
  for (int i = 0; i < 2; ++i)
    #pragma unroll
    for (int j = 0; j < 4; ++j)
      #pragma unroll
      for (int rr = 0; rr < 4; ++rr) {
        int row = arow0 + wave * 32 + i * 16 + g * 4 + rr;
        int col = brow0 + j * 16 + r16;
        float v = acc[i][j][rr];
        if (mode == 1) {
          if (row < Mr) C1[(size_t)row * 1024 + col] = f2bf(v);
        } else {
          if (col < 1024) C1[(size_t)row * 1024 + col] = f2bf(v);
          else            C2[(size_t)(col - 1024) * M_KV + row] = f2bf(v);
        }
      }
}

// ---------- output projection GEMM: 64x64 tiles (512 blocks, 5/CU), f32 out ----------
__global__ __launch_bounds__(256) void gemm_out_kernel(
    const unsigned short* __restrict__ A, const unsigned short* __restrict__ B,
    float* __restrict__ C1) {
  __shared__ unsigned short As[2][64][64];
  __shared__ unsigned short Bs[2][64][64];
  int tid  = threadIdx.x;
  int wave = tid >> 6, lane = tid & 63;
  int wr = wave >> 1, wc = wave & 1;
  int g = lane >> 4, r16 = lane & 15;
  int arow0 = blockIdx.x * 64;
  int brow0 = blockIdx.y * 64;

  auto stage = [&](int buf, int kt) {
    #pragma unroll
    for (int n = 0; n < 2; ++n) {
      int seg  = wave * 2 + n;
      int rloc = seg * 8 + (lane >> 3);
      int cbyte = ((lane & 7) << 4) ^ ((rloc & 7) << 4);
      const unsigned short* gpA = A + (size_t)(arow0 + rloc) * KDIM + kt + (cbyte >> 1);
      __builtin_amdgcn_global_load_lds((gbyte_t*)(const void*)gpA,
                                       (lbyte_t*)(void*)&As[buf][seg * 8][0], 16, 0, 0);
      const unsigned short* gpB = B + (size_t)(brow0 + rloc) * KDIM + kt + (cbyte >> 1);
      __builtin_amdgcn_global_load_lds((gbyte_t*)(const void*)gpB,
                                       (lbyte_t*)(void*)&Bs[buf][seg * 8][0], 16, 0, 0);
    }
  };

  f32x4 acc[2][2] = {{{0,0,0,0},{0,0,0,0}},{{0,0,0,0},{0,0,0,0}}};

  stage(0, 0);
  asm volatile("s_waitcnt vmcnt(0)" ::: "memory");
  __syncthreads();

  int buf = 0;
  for (int t = 0; t < 16; ++t) {
    if (t < 15) stage(buf ^ 1, (t + 1) * 64);
    bf16x8 af[2][2], bfr[2][2];
    #pragma unroll
    for (int i = 0; i < 2; ++i)
      #pragma unroll
      for (int kk = 0; kk < 2; ++kk) {
        int r = wr * 32 + i * 16 + r16;
        int cb = ((kk << 6) | (g << 4)) ^ ((r & 7) << 4);
        af[i][kk] = *(const bf16x8*)((const char*)&As[buf][r][0] + cb);
      }
    #pragma unroll
    for (int j = 0; j < 2; ++j)
      #pragma unroll
      for (int kk = 0; kk < 2; ++kk) {
        int r = wc * 32 + j * 16 + r16;
        int cb = ((kk << 6) | (g << 4)) ^ ((r & 7) << 4);
        bfr[j][kk] = *(const bf16x8*)((const char*)&Bs[buf][r][0] + cb);
      }
    __builtin_amdgcn_s_setprio(1);
    #pragma unroll
    for (int kk = 0; kk < 2; ++kk)
      #pragma unroll
      for (int i = 0; i < 2; ++i)
        #pragma unroll
        for (int j = 0; j < 2; ++j)
          acc[i][j] = __builtin_amdgcn_mfma_f32_16x16x32_bf16(af[i][kk], bfr[j][kk], acc[i][j], 0, 0, 0);
    __builtin_amdgcn_s_setprio(0);
    if (t < 15) {
      asm volatile("s_waitcnt vmcnt(0)" ::: "memory");
      __syncthreads();
      buf ^= 1;
    }
  }

  #pragma unroll
  for (int i = 0; i < 2; ++i)
    #pragma unroll
    for (int j = 0; j < 2; ++j)
      #pragma unroll
      for (int rr = 0; rr < 4; ++rr) {
        int row = arow0 + wr * 32 + i * 16 + g * 4 + rr;
        int col = brow0 + wc * 32 + j * 16 + r16;
        C1[(size_t)row * 1024 + col] = acc[i][j][rr];
      }
}

// ---------- fused causal attention, MFMA, split-KV, LDS-pipelined, phase-split waits ----------
// Stage issue order: k(2), v(2), pe(4). Bottom wait: vmcnt(6) -> only k retired (free,
// issued a full tile earlier). Mid-tile wait (after content, before pos reads): vmcnt(8)
// retires PREVIOUS tile's v+pe (had a full tile + content phase of cover). Last tile: vmcnt(0).
// Barrier-mediated -> cross-wave staging race-free.
__global__ __launch_bounds__(256, 2) void attn_mfma_kernel(
    const unsigned short* __restrict__ qb, const unsigned short* __restrict__ kb,
    const unsigned short* __restrict__ vt, const unsigned short* __restrict__ pe,
    unsigned short* __restrict__ ctx, float* __restrict__ part) {
  int ord  = (int)blockIdx.x;
  int h    = ord & 15;
  int widx = 79 - (ord >> 4);               // heavy chunks dispatched first
  int b, c;
  if (widx < 8)       { b = widx;                                  c = 0; }
  else if (widx < 24) { int t2 = widx - 8;  b = 8  + (t2 >> 1);    c = t2 & 1; }
  else if (widx < 48) { int t2 = widx - 24; int q3 = t2 / 3; b = 16 + q3; c = t2 - 3 * q3; }
  else                { int t2 = widx - 48; b = 24 + (t2 >> 2);    c = t2 & 3; }
  int n0   = b * 64;
  int nc   = (b < 8) ? 1 : (b >> 3) + 1;
  int t0   = c * 8;
  int tend = min(t0 + 8, b + 1);

  int wave = threadIdx.x >> 6;
  int lane = threadIdx.x & 63;
  int g    = lane >> 4;       // 0..3
  int r16  = lane & 15;       // 0..15

  __shared__ unsigned short Ks[2][64][64];     // 16 KB  k tile   [j-local][d]
  __shared__ unsigned short Vs[2][64][64];     // 16 KB  v tile   [d-local][j-local]
  __shared__ unsigned short PEs[2][128][64];   // 32 KB  pe band  [band-local][d]
  __shared__ unsigned short W_lds[4][16][72];  // 9.2 KB per-wave W

  const unsigned short* qrow = qb + (size_t)(n0 + wave * 16 + r16) * DIM + h * 64 + g * 8;
  bf16x8 aq0 = *(const bf16x8*)(qrow);
  bf16x8 aq1 = *(const bf16x8*)(qrow + 32);

  union { unsigned short u[8]; bf16x8 v; } one_u;
  #pragma unroll
  for (int i = 0; i < 8; ++i) one_u.u[i] = 0x3F80;   // bf16 1.0
  bf16x8 ones = one_u.v;

  f32x4 acc[4] = {{0,0,0,0},{0,0,0,0},{0,0,0,0},{0,0,0,0}};
  f32x4 lacc = {0,0,0,0};

  // issue order matters: k (oldest 2), then v, then pe (newest 4)
  auto stage = [&](int bufn, int tilen) {
    int m0n = tilen * 64;
    int prb = n0 - m0n;
    #pragma unroll
    for (int n = 0; n < 2; ++n) {
      int seg  = wave * 2 + n;
      int rloc = seg * 8 + (lane >> 3);
      int cbyte = ((lane & 7) << 4) ^ ((rloc & 7) << 4);
      const unsigned short* gpk = kb + (size_t)(m0n + rloc) * KDIM + h * 64 + (cbyte >> 1);
      __builtin_amdgcn_global_load_lds((gbyte_t*)(const void*)gpk,
                                       (lbyte_t*)(void*)&Ks[bufn][seg * 8][0], 16, 0, 0);
    }
    #pragma unroll
    for (int n = 0; n < 2; ++n) {
      int seg  = wave * 2 + n;
      int rloc = seg * 8 + (lane >> 3);
      int cbyte = ((lane & 7) << 4) ^ ((rloc & 7) << 4);
      const unsigned short* gpv = vt + (size_t)(h * 64 + rloc) * M_KV + m0n + (cbyte >> 1);
      __builtin_amdgcn_global_load_lds((gbyte_t*)(const void*)gpv,
                                       (lbyte_t*)(void*)&Vs[bufn][seg * 8][0], 16, 0, 0);
    }
    #pragma unroll
    for (int n = 0; n < 4; ++n) {
      int seg  = wave * 4 + n;
      int rloc = seg * 8 + (lane >> 3);
      int cbyte = ((lane & 7) << 4) ^ ((rloc & 7) << 4);
      const unsigned short* gpp = pe + (size_t)(prb + rloc) * KDIM + h * 64 + (cbyte >> 1);
      __builtin_amdgcn_global_load_lds((gbyte_t*)(const void*)gpp,
                                       (lbyte_t*)(void*)&PEs[bufn][seg * 8][0], 16, 0, 0);
    }
  };

  int srcl[4]; bool hi_sel[4];
  #pragma unroll
  for (int rr = 0; rr < 4; ++rr) {
    srcl[rr]   = (g << 4) | ((g * 4 + rr + 63 - r16) & 15);
    hi_sel[rr] = (g * 4 + rr) > r16;
  }
  int sw = (r16 & 7) << 4;                     // read-side swizzle

  stage(0, t0);
  asm volatile("s_waitcnt vmcnt(0)" ::: "memory");
  __syncthreads();

  int buf = 0;
  for (int tile = t0; tile < tend; ++tile) {
    int m0 = tile * 64;
    bool more = (tile + 1 < tend);
    if (more) stage(buf ^ 1, tile + 1);

    // ---- content S strip (16 x 64): 8 ds_read_b128 + 8 MFMA (Ks[buf] guaranteed) ----
    f32x4 s[4];
    __builtin_amdgcn_s_setprio(1);
    #pragma unroll
    for (int ct = 0; ct < 4; ++ct) {
      const char* kbase = (const char*)&Ks[buf][ct * 16 + r16][0];
      bf16x8 k0 = *(const bf16x8*)(kbase + (((g << 4)) ^ sw));
      bf16x8 k1 = *(const bf16x8*)(kbase + ((64 | (g << 4)) ^ sw));
      f32x4 z = {0,0,0,0};
      z = __builtin_amdgcn_mfma_f32_16x16x32_bf16(aq0, k0, z, 0, 0, 0);
      z = __builtin_amdgcn_mfma_f32_16x16x32_bf16(aq1, k1, z, 0, 0, 0);
      s[ct] = z;
    }
    __builtin_amdgcn_s_setprio(0);

    // ---- mid-phase wait: previous tile's v+pe retired (or full drain on last tile) ----
    if (more) { asm volatile("s_waitcnt vmcnt(8)" ::: "memory"); }
    else      { asm volatile("s_waitcnt vmcnt(0)" ::: "memory"); }
    __builtin_amdgcn_s_barrier();
    __builtin_amdgcn_sched_barrier(0);

    // ---- position P^T: 10 reads + 10 MFMA (PEs[buf] now guaranteed) ----
    f32x4 z2[5];
    __builtin_amdgcn_s_setprio(1);
    #pragma unroll
    for (int cp = 0; cp < 5; ++cp) {
      const char* pbase = (const char*)&PEs[buf][wave * 16 + cp * 16 + r16][0];
      bf16x8 p0 = *(const bf16x8*)(pbase + (((g << 4)) ^ sw));
      bf16x8 p1 = *(const bf16x8*)(pbase + ((64 | (g << 4)) ^ sw));
      f32x4 z = {0,0,0,0};
      z = __builtin_amdgcn_mfma_f32_16x16x32_bf16(aq0, p0, z, 0, 0, 0);
      z = __builtin_amdgcn_mfma_f32_16x16x32_bf16(aq1, p1, z, 0, 0, 0);
      z2[cp] = z;
    }
    __builtin_amdgcn_s_setprio(0);

    // ---- in-register band gather + causal mask + exp ----
    bool diag = (m0 == n0);
    #pragma unroll
    for (int ct = 0; ct < 4; ++ct) {
      #pragma unroll
      for (int rr = 0; rr < 4; ++rr) {
        float vhi = __shfl(z2[4 - ct][rr], srcl[rr], 64);
        float vlo = __shfl(z2[3 - ct][rr], srcl[rr], 64);
        float p   = hi_sel[rr] ? vhi : vlo;
        int il = g * 4 + rr;
        int it = wave * 16 + il;
        int jt = ct * 16 + r16;
        float val = s[ct][rr] + p;
        if (diag && jt > it) val = -1e30f;
        s[ct][rr] = __expf(val);
      }
    }

    // ---- W (bf16) to LDS, reread as PV A-fragments (wave-private) ----
    #pragma unroll
    for (int ct = 0; ct < 4; ++ct)
      #pragma unroll
      for (int rr = 0; rr < 4; ++rr)
        W_lds[wave][g * 4 + rr][ct * 16 + r16] = f2bf(s[ct][rr]);
    bf16x8 aw0 = *(const bf16x8*)(&W_lds[wave][r16][g * 8]);
    bf16x8 aw1 = *(const bf16x8*)(&W_lds[wave][r16][g * 8 + 32]);

    // ---- PV: 8 ds_read_b128 + 10 MFMA (Vs[buf] covered by mid-phase wait) ----
    __builtin_amdgcn_s_setprio(1);
    #pragma unroll
    for (int ct = 0; ct < 4; ++ct) {
      const char* vbase = (const char*)&Vs[buf][ct * 16 + r16][0];
      bf16x8 v0 = *(const bf16x8*)(vbase + (((g << 4)) ^ sw));
      bf16x8 v1 = *(const bf16x8*)(vbase + ((64 | (g << 4)) ^ sw));
      f32x4 a = acc[ct];
      a = __builtin_amdgcn_mfma_f32_16x16x32_bf16(aw0, v0, a, 0, 0, 0);
      a = __builtin_amdgcn_mfma_f32_16x16x32_bf16(aw1, v1, a, 0, 0, 0);
      acc[ct] = a;
    }
    lacc = __builtin_amdgcn_mfma_f32_16x16x32_bf16(aw0, ones, lacc, 0, 0, 0);
    lacc = __builtin_amdgcn_mfma_f32_16x16x32_bf16(aw1, ones, lacc, 0, 0, 0);
    __builtin_amdgcn_s_setprio(0);

    // ---- bottom: only k must be retired (counted), then barrier ----
    if (more) {
      asm volatile("s_waitcnt vmcnt(6)" ::: "memory");
      __builtin_amdgcn_s_barrier();
      __builtin_amdgcn_sched_barrier(0);
      buf ^= 1;
    }
  }

  // ---- epilogue ----
  if (nc == 1) {
    #pragma unroll
    for (int rr = 0; rr < 4; ++rr) {
      float inv = 1.0f / lacc[rr];
      #pragma unroll
      for (int ct = 0; ct < 4; ++ct) {
        int row = n0 + wave * 16 + g * 4 + rr;
        ctx[(size_t)row * DIM + h * 64 + ct * 16 + r16] = f2bf(acc[ct][rr] * inv);
      }
    }
  } else {
    float* slot = part + ((size_t)((b - 8) * 16 + h) * 4 + c) * (64 * 68);
    #pragma unroll
    for (int ct = 0; ct < 4; ++ct)
      #pragma unroll
      for (int rr = 0; rr < 4; ++rr) {
        int row = wave * 16 + g * 4 + rr;
        slot[row * 68 + ct * 16 + r16] = acc[ct][rr];
      }
    if (r16 == 0) {
      #pragma unroll
      for (int rr = 0; rr < 4; ++rr) {
        int row = wave * 16 + g * 4 + rr;
        slot[row * 68 + 64] = lacc[rr];
      }
    }
  }
}

// ---------- merge split-KV partials (q-tiles b>=8) ----------
__global__ __launch_bounds__(256) void combine_kernel(const float* __restrict__ part,
                                                      unsigned short* __restrict__ ctx) {
  int bb = blockIdx.x;       // 0..23 -> b = bb+8
  int h  = blockIdx.y;
  int b  = bb + 8;
  int nc = (b >> 3) + 1;     // 2..4
  int t  = threadIdx.x;
  int row = t >> 2, q = t & 3;
  const float* base = part + ((size_t)(bb * 16 + h) * 4) * (64 * 68) + row * 68;
  float lstar = 0.0f;
  for (int c2 = 0; c2 < nc; ++c2) lstar += base[c2 * 4352 + 64];
  float inv = 1.0f / lstar;
  for (int cc = 0; cc < 16; ++cc) {
    int col = q * 16 + cc;
    float o = 0.0f;
    for (int c2 = 0; c2 < nc; ++c2) o += base[c2 * 4352 + col];
    ctx[(size_t)(b * 64 + row) * DIM + h * 64 + col] = f2bf(o * inv);
  }
}

extern "C" void kernel_launch(void* const* d_in, const int* in_sizes, int n_in,
                              void* d_out, int out_size, void* d_ws, size_t ws_size,
                              hipStream_t stream) {
  const float* x_q    = (const float*)d_in[0];
  const float* x_kv   = (const float*)d_in[1];
  const float* to_q   = (const float*)d_in[2];
  const float* to_k   = (const float*)d_in[3];
  const float* to_v   = (const float*)d_in[4];
  const float* to_out = (const float*)d_in[5];
  const float* to_pe  = (const float*)d_in[6];

  char* ws = (char*)d_ws;
  size_t off = 0;
  auto alloc = [&](size_t bytes) -> char* {
    char* p = ws + off;
    off += (bytes + 255) & ~(size_t)255;
    return p;
  };

  unsigned short* xq_bf  = (unsigned short*)alloc((size_t)N_Q  * DIM * 2);
  unsigned short* xkv_bf = (unsigned short*)alloc((size_t)M_KV * DIM * 2);
  unsigned short* wq_bf  = (unsigned short*)alloc((size_t)DIM * DIM * 2);
  unsigned short* wkv_bf = (unsigned short*)alloc((size_t)2 * DIM * DIM * 2);  // [wk; wv]
  unsigned short* wp_bf  = (unsigned short*)alloc((size_t)DIM * DIM * 2);
  unsigned short* wo_bf  = (unsigned short*)alloc((size_t)DIM * DIM * 2);
  unsigned short* sc_bf  = (unsigned short*)alloc((size_t)PEBUF * DIM * 2);
  unsigned short* q_bf   = (unsigned short*)alloc((size_t)N_Q  * DIM * 2);
  unsigned short* k_bf   = (unsigned short*)alloc((size_t)M_KV * DIM * 2);
  unsigned short* vt_bf  = (unsigned short*)alloc((size_t)DIM * M_KV * 2);
  unsigned short* pe_bf  = (unsigned short*)alloc((size_t)PEBUF * DIM * 2);
  unsigned short* ctx_bf = (unsigned short*)alloc((size_t)N_Q * DIM * 2);
  float*          part   = (float*)alloc((size_t)24 * 16 * 4 * 64 * 68 * 4);

  // fused prep (cvt + packs + sincos)
  prep_kernel<<<11392, 256, 0, stream>>>(x_q, x_kv, to_q, to_k, to_v, to_pe, to_out,
                                         xq_bf, xkv_bf, wq_bf, wkv_bf, wp_bf, wo_bf, sc_bf);

  // fused input projections (q, k|vt, pe), 128x64 tiles, XCD-chunked (R12 config)
  gemm_in_kernel<<<1040, 256, 0, stream>>>(xq_bf, xkv_bf, sc_bf, wq_bf, wkv_bf, wp_bf,
                                           q_bf, k_bf, vt_bf, pe_bf);

  // fused attention (split-KV, LDS pipeline, phase-split counted waits) + combine
  attn_mfma_kernel<<<1280, 256, 0, stream>>>(q_bf, k_bf, vt_bf, pe_bf, ctx_bf, part);
  combine_kernel<<<dim3(24, NH), 256, 0, stream>>>(part, ctx_bf);

  // output projection -> d_out (f32)
  gemm_out_kernel<<<dim3(32, 16), 256, 0, stream>>>(ctx_bf, wo_bf, (float*)d_out);
}

// Round 15
// 133.680 us; speedup vs baseline: 1.0688x; 1.0231x over previous
//
#include <hip/hip_runtime.h>
#include <hip/hip_bf16.h>

// Problem constants
#define N_Q   2048
#define M_KV  2048
#define DIM   1024
#define NH    16
#define DHEAD 64
#define KDIM  1024
#define PEROWS 2112   // pe_rel rows actually used: global rows 1984..4094 -> local 0..2111
#define PEBUF  2176

typedef __attribute__((ext_vector_type(8))) __bf16 bf16x8;
typedef __attribute__((ext_vector_type(4))) float  f32x4;

typedef __attribute__((address_space(1))) const unsigned char gbyte_t;
typedef __attribute__((address_space(3))) unsigned char lbyte_t;

__device__ __forceinline__ unsigned short f2bf(float f) {
  union { float f; unsigned u; } v; v.f = f;
  unsigned u = v.u;
  u = u + 0x7fffu + ((u >> 16) & 1u);   // RNE
  return (unsigned short)(u >> 16);
}

// ---------- single fused prep kernel ----------
#define PREP_A 524288
#define PREP_B 1048576
#define PREP_C 2097152
#define PREP_D 2359296
#define PREP_E 2916352
__global__ __launch_bounds__(256) void prep_kernel(
    const float* __restrict__ x_q, const float* __restrict__ x_kv,
    const float* __restrict__ to_q, const float* __restrict__ to_k,
    const float* __restrict__ to_v, const float* __restrict__ to_pe,
    const float* __restrict__ to_out,
    unsigned short* __restrict__ xq_bf, unsigned short* __restrict__ xkv_bf,
    unsigned short* __restrict__ wq_bf, unsigned short* __restrict__ wkv_bf,
    unsigned short* __restrict__ wp_bf, unsigned short* __restrict__ wo_bf,
    unsigned short* __restrict__ sc_bf) {
  int gid = blockIdx.x * 256 + threadIdx.x;
  if (gid < PREP_B) {            // cvt x_q / x_kv, float4 -> 4x bf16
    const float* src = (gid < PREP_A) ? x_q : x_kv;
    unsigned short* dst = (gid < PREP_A) ? xq_bf : xkv_bf;
    int e4 = (gid < PREP_A ? gid : gid - PREP_A) * 4;
    float4 v = *(const float4*)(src + e4);
    ushort4 o = { f2bf(v.x), f2bf(v.y), f2bf(v.z), f2bf(v.w) };
    *(ushort4*)(dst + e4) = o;
  } else if (gid < PREP_C) {     // pack4: (DHEAD,NH,DIM) -> (h*64+d, DIM)
    int e = gid - PREP_B;
    int which = e >> 18, inner = e & 262143;
    int e4 = inner * 4;
    int j = e4 >> 10, b = e4 & 1023;
    int d = j & 63, h = j >> 6;
    const float* w = (which == 0) ? to_q : (which == 1) ? to_k : (which == 2) ? to_v : to_pe;
    unsigned short* o = (which == 0) ? wq_bf : (which == 1) ? wkv_bf
                       : (which == 2) ? (wkv_bf + (size_t)DIM * DIM) : wp_bf;
    float4 v = *(const float4*)(w + (size_t)(d * NH + h) * DIM + b);
    ushort4 u = { f2bf(v.x), f2bf(v.y), f2bf(v.z), f2bf(v.w) };
    *(ushort4*)(o + e4) = u;
  } else if (gid < PREP_D) {     // pack_wo: (DIM,DHEAD,NH) -> (DIM, h*64+c)
    int e4 = (gid - PREP_C) * 4;
    int dd = e4 >> 10, jc = e4 & 1023;
    int c = jc & 63, h = jc >> 6;
    const float* base = to_out + (size_t)(dd * DHEAD + c) * NH + h;
    ushort4 u = { f2bf(base[0]), f2bf(base[16]), f2bf(base[32]), f2bf(base[48]) };
    *(ushort4*)(wo_bf + e4) = u;
  } else if (gid < PREP_E) {     // sincos: row r, 2 k2-cols per thread
    int e = gid - PREP_D;
    int r = e >> 8, t8 = e & 255;
    float ph0base = (float)(r - 63);
    unsigned short ss[2], cc[2];
    #pragma unroll
    for (int i = 0; i < 2; ++i) {
      int k2 = t8 * 2 + i;
      float invf = __expf((float)k2 * (-9.210340371976184f / 512.0f));  // 10000^(-k2/512)
      float s, c;
      __sincosf(ph0base * invf, &s, &c);
      ss[i] = f2bf(s); cc[i] = f2bf(c);
    }
    unsigned short* row = sc_bf + (size_t)r * DIM;
    *(unsigned int*)(row + t8 * 2)       = (unsigned)ss[0] | ((unsigned)ss[1] << 16);
    *(unsigned int*)(row + t8 * 2 + 512) = (unsigned)cc[0] | ((unsigned)cc[1] << 16);
  }
}

// ---------- fused input GEMMs, 128x64 tiles, 1040 blocks, XCD-chunked swizzle ----------
// R12-proven config: 2-buf, 48 KB LDS -> 3 blocks/CU.
__global__ __launch_bounds__(256) void gemm_in_kernel(
    const unsigned short* __restrict__ xq, const unsigned short* __restrict__ xkv,
    const unsigned short* __restrict__ sc,
    const unsigned short* __restrict__ wq, const unsigned short* __restrict__ wkv,
    const unsigned short* __restrict__ wp,
    unsigned short* __restrict__ qout, unsigned short* __restrict__ kout,
    unsigned short* __restrict__ vtout, unsigned short* __restrict__ peout) {
  int bid0 = (int)blockIdx.x;
  int bid  = (bid0 & 7) * 130 + (bid0 >> 3);   // bijective: 1040 = 8 * 130
  const unsigned short *A, *B; unsigned short *C1, *C2;
  int Mr, maxBrow, mode, ax, by;
  if (bid < 256)      { int t = bid;       ax = t & 15; by = t >> 4; A = xq;  B = wq;  C1 = qout;  C2 = nullptr; Mr = N_Q;    maxBrow = DIM - 1;     mode = 1; }
  else if (bid < 768) { int t = bid - 256; ax = t & 15; by = t >> 4; A = xkv; B = wkv; C1 = kout;  C2 = vtout;   Mr = M_KV;   maxBrow = 2 * DIM - 1; mode = 3; }
  else                { int t = bid - 768; ax = t % 17; by = t / 17; A = sc;  B = wp;  C1 = peout; C2 = nullptr; Mr = PEROWS; maxBrow = DIM - 1;     mode = 1; }

  __shared__ unsigned short As[2][128][64];
  __shared__ unsigned short Bs[2][64][64];
  int tid  = threadIdx.x;
  int wave = tid >> 6, lane = tid & 63;
  int g = lane >> 4, r16 = lane & 15;
  int arow0 = ax * 128;
  int brow0 = by * 64;
  int amax  = Mr - 1;

  auto stage = [&](int buf, int kt) {
    #pragma unroll
    for (int n = 0; n < 4; ++n) {
      int seg  = wave * 4 + n;
      int rloc = seg * 8 + (lane >> 3);
      int cbyte = ((lane & 7) << 4) ^ ((rloc & 7) << 4);
      int grow = min(arow0 + rloc, amax);
      const unsigned short* gp = A + (size_t)grow * KDIM + kt + (cbyte >> 1);
      __builtin_amdgcn_global_load_lds((gbyte_t*)(const void*)gp,
                                       (lbyte_t*)(void*)&As[buf][seg * 8][0], 16, 0, 0);
    }
    #pragma unroll
    for (int n = 0; n < 2; ++n) {
      int seg  = wave * 2 + n;
      int rloc = seg * 8 + (lane >> 3);
      int cbyte = ((lane & 7) << 4) ^ ((rloc & 7) << 4);
      int grow = min(brow0 + rloc, maxBrow);
      const unsigned short* gp = B + (size_t)grow * KDIM + kt + (cbyte >> 1);
      __builtin_amdgcn_global_load_lds((gbyte_t*)(const void*)gp,
                                       (lbyte_t*)(void*)&Bs[buf][seg * 8][0], 16, 0, 0);
    }
  };

  f32x4 acc[2][4];
  #pragma unroll
  for (int i = 0; i < 2; ++i)
    #pragma unroll
    for (int j = 0; j < 4; ++j) acc[i][j] = (f32x4){0,0,0,0};

  stage(0, 0);
  asm volatile("s_waitcnt vmcnt(0)" ::: "memory");
  __syncthreads();

  int buf = 0;
  for (int t = 0; t < 16; ++t) {
    if (t < 15) stage(buf ^ 1, (t + 1) * 64);

    bf16x8 af[2][2], bfr[4][2];
    #pragma unroll
    for (int i = 0; i < 2; ++i)
      #pragma unroll
      for (int kk = 0; kk < 2; ++kk) {
        int r = wave * 32 + i * 16 + r16;
        int cb = ((kk << 6) | (g << 4)) ^ ((r & 7) << 4);
        af[i][kk] = *(const bf16x8*)((const char*)&As[buf][r][0] + cb);
      }
    #pragma unroll
    for (int j = 0; j < 4; ++j)
      #pragma unroll
      for (int kk = 0; kk < 2; ++kk) {
        int r = j * 16 + r16;
        int cb = ((kk << 6) | (g << 4)) ^ ((r & 7) << 4);
        bfr[j][kk] = *(const bf16x8*)((const char*)&Bs[buf][r][0] + cb);
      }
    __builtin_amdgcn_s_setprio(1);
    #pragma unroll
    for (int kk = 0; kk < 2; ++kk)
      #pragma unroll
      for (int i = 0; i < 2; ++i)
        #pragma unroll
        for (int j = 0; j < 4; ++j)
          acc[i][j] = __builtin_amdgcn_mfma_f32_16x16x32_bf16(af[i][kk], bfr[j][kk], acc[i][j], 0, 0, 0);
    __builtin_amdgcn_s_setprio(0);

    if (t < 15) {
      asm volatile("s_waitcnt vmcnt(0)" ::: "memory");
      __syncthreads();
      buf ^= 1;
    }
  }

  #pragma unroll
  for (int i = 0; i < 2; ++i)
    #pragma unroll
    for (int j = 0; j < 4; ++j)
      #pragma unroll
      for (int rr = 0; rr < 4; ++rr) {
        int row = arow0 + wave * 32 + i * 16 + g * 4 + rr;
        int col = brow0 + j * 16 + r16;
        float v = acc[i][j][rr];
        if (mode == 1) {
          if (row < Mr) C1[(size_t)row * 1024 + col] = f2bf(v);
        } else {
          if (col < 1024) C1[(size_t)row * 1024 + col] = f2bf(v);
          else            C2[(size_t)(col - 1024) * M_KV + row] = f2bf(v);
        }
      }
}

// ---------- output projection GEMM: 64x64 tiles (512 blocks, 5/CU), f32 out ----------
__global__ __launch_bounds__(256) void gemm_out_kernel(
    const unsigned short* __restrict__ A, const unsigned short* __restrict__ B,
    float* __restrict__ C1) {
  __shared__ unsigned short As[2][64][64];
  __shared__ unsigned short Bs[2][64][64];
  int tid  = threadIdx.x;
  int wave = tid >> 6, lane = tid & 63;
  int wr = wave >> 1, wc = wave & 1;
  int g = lane >> 4, r16 = lane & 15;
  int arow0 = blockIdx.x * 64;
  int brow0 = blockIdx.y * 64;

  auto stage = [&](int buf, int kt) {
    #pragma unroll
    for (int n = 0; n < 2; ++n) {
      int seg  = wave * 2 + n;
      int rloc = seg * 8 + (lane >> 3);
      int cbyte = ((lane & 7) << 4) ^ ((rloc & 7) << 4);
      const unsigned short* gpA = A + (size_t)(arow0 + rloc) * KDIM + kt + (cbyte >> 1);
      __builtin_amdgcn_global_load_lds((gbyte_t*)(const void*)gpA,
                                       (lbyte_t*)(void*)&As[buf][seg * 8][0], 16, 0, 0);
      const unsigned short* gpB = B + (size_t)(brow0 + rloc) * KDIM + kt + (cbyte >> 1);
      __builtin_amdgcn_global_load_lds((gbyte_t*)(const void*)gpB,
                                       (lbyte_t*)(void*)&Bs[buf][seg * 8][0], 16, 0, 0);
    }
  };

  f32x4 acc[2][2] = {{{0,0,0,0},{0,0,0,0}},{{0,0,0,0},{0,0,0,0}}};

  stage(0, 0);
  asm volatile("s_waitcnt vmcnt(0)" ::: "memory");
  __syncthreads();

  int buf = 0;
  for (int t = 0; t < 16; ++t) {
    if (t < 15) stage(buf ^ 1, (t + 1) * 64);
    bf16x8 af[2][2], bfr[2][2];
    #pragma unroll
    for (int i = 0; i < 2; ++i)
      #pragma unroll
      for (int kk = 0; kk < 2; ++kk) {
        int r = wr * 32 + i * 16 + r16;
        int cb = ((kk << 6) | (g << 4)) ^ ((r & 7) << 4);
        af[i][kk] = *(const bf16x8*)((const char*)&As[buf][r][0] + cb);
      }
    #pragma unroll
    for (int j = 0; j < 2; ++j)
      #pragma unroll
      for (int kk = 0; kk < 2; ++kk) {
        int r = wc * 32 + j * 16 + r16;
        int cb = ((kk << 6) | (g << 4)) ^ ((r & 7) << 4);
        bfr[j][kk] = *(const bf16x8*)((const char*)&Bs[buf][r][0] + cb);
      }
    __builtin_amdgcn_s_setprio(1);
    #pragma unroll
    for (int kk = 0; kk < 2; ++kk)
      #pragma unroll
      for (int i = 0; i < 2; ++i)
        #pragma unroll
        for (int j = 0; j < 2; ++j)
          acc[i][j] = __builtin_amdgcn_mfma_f32_16x16x32_bf16(af[i][kk], bfr[j][kk], acc[i][j], 0, 0, 0);
    __builtin_amdgcn_s_setprio(0);
    if (t < 15) {
      asm volatile("s_waitcnt vmcnt(0)" ::: "memory");
      __syncthreads();
      buf ^= 1;
    }
  }

  #pragma unroll
  for (int i = 0; i < 2; ++i)
    #pragma unroll
    for (int j = 0; j < 2; ++j)
      #pragma unroll
      for (int rr = 0; rr < 4; ++rr) {
        int row = arow0 + wr * 32 + i * 16 + g * 4 + rr;
        int col = brow0 + wc * 32 + j * 16 + r16;
        C1[(size_t)row * 1024 + col] = acc[i][j][rr];
      }
}

// ---------- fused causal attention: 3 blocks/CU via single-buffered V/PE ----------
// LDS 49 KB: Ks dbuf 16 + Vs single 8 + PEs single 16 + W 9.2.
// Per tile: content(Ks[kbuf]) -> vmcnt(pe) + barrier -> pos(PEs) -> softmax ->
// vmcnt(v) + barrier -> PV(Vs) -> vmcnt(0) [stale k only, free] + barrier ->
// issue pe(t+1), v(t+1), k(t+2). Every wait retires this wave's own loads before
// the shared barrier -> cross-wave LDS visibility safe. W_lds wave-private.
__global__ __launch_bounds__(256, 3) void attn_mfma_kernel(
    const unsigned short* __restrict__ qb, const unsigned short* __restrict__ kb,
    const unsigned short* __restrict__ vt, const unsigned short* __restrict__ pe,
    unsigned short* __restrict__ ctx, float* __restrict__ part) {
  int ord  = (int)blockIdx.x;
  int h    = ord & 15;
  int widx = 79 - (ord >> 4);               // heavy chunks dispatched first
  int b, c;
  if (widx < 8)       { b = widx;                                  c = 0; }
  else if (widx < 24) { int t2 = widx - 8;  b = 8  + (t2 >> 1);    c = t2 & 1; }
  else if (widx < 48) { int t2 = widx - 24; int q3 = t2 / 3; b = 16 + q3; c = t2 - 3 * q3; }
  else                { int t2 = widx - 48; b = 24 + (t2 >> 2);    c = t2 & 3; }
  int n0   = b * 64;
  int nc   = (b < 8) ? 1 : (b >> 3) + 1;
  int t0   = c * 8;
  int tend = min(t0 + 8, b + 1);

  int wave = threadIdx.x >> 6;
  int lane = threadIdx.x & 63;
  int g    = lane >> 4;       // 0..3
  int r16  = lane & 15;       // 0..15

  __shared__ unsigned short Ks[2][64][64];     // 16 KB double (k for next tile)
  __shared__ unsigned short Vs[64][64];        // 8 KB single (current tile)
  __shared__ unsigned short PEs[128][64];      // 16 KB single (current tile)
  __shared__ unsigned short W_lds[4][16][72];  // 9.2 KB per-wave W

  const unsigned short* qrow = qb + (size_t)(n0 + wave * 16 + r16) * DIM + h * 64 + g * 8;
  bf16x8 aq0 = *(const bf16x8*)(qrow);
  bf16x8 aq1 = *(const bf16x8*)(qrow + 32);

  union { unsigned short u[8]; bf16x8 v; } one_u;
  #pragma unroll
  for (int i = 0; i < 8; ++i) one_u.u[i] = 0x3F80;   // bf16 1.0
  bf16x8 ones = one_u.v;

  f32x4 acc[4] = {{0,0,0,0},{0,0,0,0},{0,0,0,0},{0,0,0,0}};
  f32x4 lacc = {0,0,0,0};

  auto stage_pe = [&](int tilen) {
    int prb = n0 - tilen * 64;
    #pragma unroll
    for (int n = 0; n < 4; ++n) {
      int seg  = wave * 4 + n;
      int rloc = seg * 8 + (lane >> 3);
      int cbyte = ((lane & 7) << 4) ^ ((rloc & 7) << 4);
      const unsigned short* gpp = pe + (size_t)(prb + rloc) * KDIM + h * 64 + (cbyte >> 1);
      __builtin_amdgcn_global_load_lds((gbyte_t*)(const void*)gpp,
                                       (lbyte_t*)(void*)&PEs[seg * 8][0], 16, 0, 0);
    }
  };
  auto stage_v = [&](int tilen) {
    int m0n = tilen * 64;
    #pragma unroll
    for (int n = 0; n < 2; ++n) {
      int seg  = wave * 2 + n;
      int rloc = seg * 8 + (lane >> 3);
      int cbyte = ((lane & 7) << 4) ^ ((rloc & 7) << 4);
      const unsigned short* gpv = vt + (size_t)(h * 64 + rloc) * M_KV + m0n + (cbyte >> 1);
      __builtin_amdgcn_global_load_lds((gbyte_t*)(const void*)gpv,
                                       (lbyte_t*)(void*)&Vs[seg * 8][0], 16, 0, 0);
    }
  };
  auto stage_k = [&](int kb_, int tilen) {
    int m0n = tilen * 64;
    #pragma unroll
    for (int n = 0; n < 2; ++n) {
      int seg  = wave * 2 + n;
      int rloc = seg * 8 + (lane >> 3);
      int cbyte = ((lane & 7) << 4) ^ ((rloc & 7) << 4);
      const unsigned short* gpk = kb + (size_t)(m0n + rloc) * KDIM + h * 64 + (cbyte >> 1);
      __builtin_amdgcn_global_load_lds((gbyte_t*)(const void*)gpk,
                                       (lbyte_t*)(void*)&Ks[kb_][seg * 8][0], 16, 0, 0);
    }
  };

  int srcl[4]; bool hi_sel[4];
  #pragma unroll
  for (int rr = 0; rr < 4; ++rr) {
    srcl[rr]   = (g << 4) | ((g * 4 + rr + 63 - r16) & 15);
    hi_sel[rr] = (g * 4 + rr) > r16;
  }
  int sw = (r16 & 7) << 4;                     // read-side swizzle

  // prologue: current-tile pe/v/k; next-tile k if it exists
  stage_pe(t0);
  stage_v(t0);
  stage_k(0, t0);
  if (t0 + 1 < tend) {
    stage_k(1, t0 + 1);
    asm volatile("s_waitcnt vmcnt(2)" ::: "memory");   // retire pe,v,k(t0); keep k(t0+1)
  } else {
    asm volatile("s_waitcnt vmcnt(0)" ::: "memory");
  }
  __syncthreads();

  int kbuf = 0;
  for (int tile = t0; tile < tend; ++tile) {
    int m0 = tile * 64;
    bool more  = (tile + 1 < tend);
    bool more2 = (tile + 2 < tend);

    // ---- content S strip (16 x 64): 8 ds_read_b128 + 8 MFMA ----
    f32x4 s[4];
    __builtin_amdgcn_s_setprio(1);
    #pragma unroll
    for (int ct = 0; ct < 4; ++ct) {
      const char* kbase = (const char*)&Ks[kbuf][ct * 16 + r16][0];
      bf16x8 k0 = *(const bf16x8*)(kbase + (((g << 4)) ^ sw));
      bf16x8 k1 = *(const bf16x8*)(kbase + ((64 | (g << 4)) ^ sw));
      f32x4 z = {0,0,0,0};
      z = __builtin_amdgcn_mfma_f32_16x16x32_bf16(aq0, k0, z, 0, 0, 0);
      z = __builtin_amdgcn_mfma_f32_16x16x32_bf16(aq1, k1, z, 0, 0, 0);
      s[ct] = z;
    }
    __builtin_amdgcn_s_setprio(0);

    // ---- mid: retire this tile's pe (keep v + maybe next-k), then barrier ----
    if (more) { asm volatile("s_waitcnt vmcnt(4)" ::: "memory"); }
    else      { asm volatile("s_waitcnt vmcnt(2)" ::: "memory"); }
    __builtin_amdgcn_s_barrier();
    __builtin_amdgcn_sched_barrier(0);

    // ---- position P^T: 10 reads + 10 MFMA (PEs now valid) ----
    f32x4 z2[5];
    __builtin_amdgcn_s_setprio(1);
    #pragma unroll
    for (int cp = 0; cp < 5; ++cp) {
      const char* pbase = (const char*)&PEs[wave * 16 + cp * 16 + r16][0];
      bf16x8 p0 = *(const bf16x8*)(pbase + (((g << 4)) ^ sw));
      bf16x8 p1 = *(const bf16x8*)(pbase + ((64 | (g << 4)) ^ sw));
      f32x4 z = {0,0,0,0};
      z = __builtin_amdgcn_mfma_f32_16x16x32_bf16(aq0, p0, z, 0, 0, 0);
      z = __builtin_amdgcn_mfma_f32_16x16x32_bf16(aq1, p1, z, 0, 0, 0);
      z2[cp] = z;
    }
    __builtin_amdgcn_s_setprio(0);

    // ---- in-register band gather + causal mask + exp ----
    bool diag = (m0 == n0);
    #pragma unroll
    for (int ct = 0; ct < 4; ++ct) {
      #pragma unroll
      for (int rr = 0; rr < 4; ++rr) {
        float vhi = __shfl(z2[4 - ct][rr], srcl[rr], 64);
        float vlo = __shfl(z2[3 - ct][rr], srcl[rr], 64);
        float p   = hi_sel[rr] ? vhi : vlo;
        int il = g * 4 + rr;
        int it = wave * 16 + il;
        int jt = ct * 16 + r16;
        float val = s[ct][rr] + p;
        if (diag && jt > it) val = -1e30f;
        s[ct][rr] = __expf(val);
      }
    }

    // ---- W (bf16) to LDS, reread as PV A-fragments (wave-private) ----
    #pragma unroll
    for (int ct = 0; ct < 4; ++ct)
      #pragma unroll
      for (int rr = 0; rr < 4; ++rr)
        W_lds[wave][g * 4 + rr][ct * 16 + r16] = f2bf(s[ct][rr]);
    bf16x8 aw0 = *(const bf16x8*)(&W_lds[wave][r16][g * 8]);
    bf16x8 aw1 = *(const bf16x8*)(&W_lds[wave][r16][g * 8 + 32]);

    // ---- pre-PV: retire this tile's v (keep next-k), then barrier ----
    if (more) { asm volatile("s_waitcnt vmcnt(2)" ::: "memory"); }
    else      { asm volatile("s_waitcnt vmcnt(0)" ::: "memory"); }
    __builtin_amdgcn_s_barrier();
    __builtin_amdgcn_sched_barrier(0);

    // ---- PV: 8 ds_read_b128 + 10 MFMA ----
    __builtin_amdgcn_s_setprio(1);
    #pragma unroll
    for (int ct = 0; ct < 4; ++ct) {
      const char* vbase = (const char*)&Vs[ct * 16 + r16][0];
      bf16x8 v0 = *(const bf16x8*)(vbase + (((g << 4)) ^ sw));
      bf16x8 v1 = *(const bf16x8*)(vbase + ((64 | (g << 4)) ^ sw));
      f32x4 a = acc[ct];
      a = __builtin_amdgcn_mfma_f32_16x16x32_bf16(aw0, v0, a, 0, 0, 0);
      a = __builtin_amdgcn_mfma_f32_16x16x32_bf16(aw1, v1, a, 0, 0, 0);
      acc[ct] = a;
    }
    lacc = __builtin_amdgcn_mfma_f32_16x16x32_bf16(aw0, ones, lacc, 0, 0, 0);
    lacc = __builtin_amdgcn_mfma_f32_16x16x32_bf16(aw1, ones, lacc, 0, 0, 0);
    __builtin_amdgcn_s_setprio(0);

    // ---- bottom: free Vs/PEs (barrier), then issue next tile's pe/v (+k(t+2)) ----
    if (more) {
      asm volatile("s_waitcnt vmcnt(0)" ::: "memory");   // only stale k(t+1) outstanding - free
      __builtin_amdgcn_s_barrier();
      __builtin_amdgcn_sched_barrier(0);
      stage_pe(tile + 1);
      stage_v(tile + 1);
      if (more2) stage_k(kbuf, tile + 2);
      kbuf ^= 1;
    }
  }

  // ---- epilogue ----
  if (nc == 1) {
    #pragma unroll
    for (int rr = 0; rr < 4; ++rr) {
      float inv = 1.0f / lacc[rr];
      #pragma unroll
      for (int ct = 0; ct < 4; ++ct) {
        int row = n0 + wave * 16 + g * 4 + rr;
        ctx[(size_t)row * DIM + h * 64 + ct * 16 + r16] = f2bf(acc[ct][rr] * inv);
      }
    }
  } else {
    float* slot = part + ((size_t)((b - 8) * 16 + h) * 4 + c) * (64 * 68);
    #pragma unroll
    for (int ct = 0; ct < 4; ++ct)
      #pragma unroll
      for (int rr = 0; rr < 4; ++rr) {
        int row = wave * 16 + g * 4 + rr;
        slot[row * 68 + ct * 16 + r16] = acc[ct][rr];
      }
    if (r16 == 0) {
      #pragma unroll
      for (int rr = 0; rr < 4; ++rr) {
        int row = wave * 16 + g * 4 + rr;
        slot[row * 68 + 64] = lacc[rr];
      }
    }
  }
}

// ---------- merge split-KV partials (q-tiles b>=8) ----------
__global__ __launch_bounds__(256) void combine_kernel(const float* __restrict__ part,
                                                      unsigned short* __restrict__ ctx) {
  int bb = blockIdx.x;       // 0..23 -> b = bb+8
  int h  = blockIdx.y;
  int b  = bb + 8;
  int nc = (b >> 3) + 1;     // 2..4
  int t  = threadIdx.x;
  int row = t >> 2, q = t & 3;
  const float* base = part + ((size_t)(bb * 16 + h) * 4) * (64 * 68) + row * 68;
  float lstar = 0.0f;
  for (int c2 = 0; c2 < nc; ++c2) lstar += base[c2 * 4352 + 64];
  float inv = 1.0f / lstar;
  for (int cc = 0; cc < 16; ++cc) {
    int col = q * 16 + cc;
    float o = 0.0f;
    for (int c2 = 0; c2 < nc; ++c2) o += base[c2 * 4352 + col];
    ctx[(size_t)(b * 64 + row) * DIM + h * 64 + col] = f2bf(o * inv);
  }
}

extern "C" void kernel_launch(void* const* d_in, const int* in_sizes, int n_in,
                              void* d_out, int out_size, void* d_ws, size_t ws_size,
                              hipStream_t stream) {
  const float* x_q    = (const float*)d_in[0];
  const float* x_kv   = (const float*)d_in[1];
  const float* to_q   = (const float*)d_in[2];
  const float* to_k   = (const float*)d_in[3];
  const float* to_v   = (const float*)d_in[4];
  const float* to_out = (const float*)d_in[5];
  const float* to_pe  = (const float*)d_in[6];

  char* ws = (char*)d_ws;
  size_t off = 0;
  auto alloc = [&](size_t bytes) -> char* {
    char* p = ws + off;
    off += (bytes + 255) & ~(size_t)255;
    return p;
  };

  unsigned short* xq_bf  = (unsigned short*)alloc((size_t)N_Q  * DIM * 2);
  unsigned short* xkv_bf = (unsigned short*)alloc((size_t)M_KV * DIM * 2);
  unsigned short* wq_bf  = (unsigned short*)alloc((size_t)DIM * DIM * 2);
  unsigned short* wkv_bf = (unsigned short*)alloc((size_t)2 * DIM * DIM * 2);  // [wk; wv]
  unsigned short* wp_bf  = (unsigned short*)alloc((size_t)DIM * DIM * 2);
  unsigned short* wo_bf  = (unsigned short*)alloc((size_t)DIM * DIM * 2);
  unsigned short* sc_bf  = (unsigned short*)alloc((size_t)PEBUF * DIM * 2);
  unsigned short* q_bf   = (unsigned short*)alloc((size_t)N_Q  * DIM * 2);
  unsigned short* k_bf   = (unsigned short*)alloc((size_t)M_KV * DIM * 2);
  unsigned short* vt_bf  = (unsigned short*)alloc((size_t)DIM * M_KV * 2);
  unsigned short* pe_bf  = (unsigned short*)alloc((size_t)PEBUF * DIM * 2);
  unsigned short* ctx_bf = (unsigned short*)alloc((size_t)N_Q * DIM * 2);
  float*          part   = (float*)alloc((size_t)24 * 16 * 4 * 64 * 68 * 4);

  // fused prep (cvt + packs + sincos)
  prep_kernel<<<11392, 256, 0, stream>>>(x_q, x_kv, to_q, to_k, to_v, to_pe, to_out,
                                         xq_bf, xkv_bf, wq_bf, wkv_bf, wp_bf, wo_bf, sc_bf);

  // fused input projections (q, k|vt, pe), 128x64 tiles, XCD-chunked
  gemm_in_kernel<<<1040, 256, 0, stream>>>(xq_bf, xkv_bf, sc_bf, wq_bf, wkv_bf, wp_bf,
                                           q_bf, k_bf, vt_bf, pe_bf);

  // fused attention (split-KV, 3 blocks/CU, single-buffered V/PE) + combine
  attn_mfma_kernel<<<1280, 256, 0, stream>>>(q_bf, k_bf, vt_bf, pe_bf, ctx_bf, part);
  combine_kernel<<<dim3(24, NH), 256, 0, stream>>>(part, ctx_bf);

  // output projection -> d_out (f32)
  gemm_out_kernel<<<dim3(32, 16), 256, 0, stream>>>(ctx_bf, wo_bf, (float*)d_out);
}

// Round 16
// 131.506 us; speedup vs baseline: 1.0865x; 1.0165x over previous
//
#include <hip/hip_runtime.h>
#include <hip/hip_bf16.h>

// Problem constants
#define N_Q   2048
#define M_KV  2048
#define DIM   1024
#define NH    16
#define DHEAD 64
#define KDIM  1024
#define PEROWS 2112   // pe_rel rows actually used: global rows 1984..4094 -> local 0..2111
#define PEBUF  2176

typedef __attribute__((ext_vector_type(8))) __bf16 bf16x8;
typedef __attribute__((ext_vector_type(4))) float  f32x4;

typedef __attribute__((address_space(1))) const unsigned char gbyte_t;
typedef __attribute__((address_space(3))) unsigned char lbyte_t;

__device__ __forceinline__ unsigned short f2bf(float f) {
  union { float f; unsigned u; } v; v.f = f;
  unsigned u = v.u;
  u = u + 0x7fffu + ((u >> 16) & 1u);   // RNE
  return (unsigned short)(u >> 16);
}

// ---------- single fused prep kernel ----------
#define PREP_A 524288
#define PREP_B 1048576
#define PREP_C 2097152
#define PREP_D 2359296
#define PREP_E 2916352
__global__ __launch_bounds__(256) void prep_kernel(
    const float* __restrict__ x_q, const float* __restrict__ x_kv,
    const float* __restrict__ to_q, const float* __restrict__ to_k,
    const float* __restrict__ to_v, const float* __restrict__ to_pe,
    const float* __restrict__ to_out,
    unsigned short* __restrict__ xq_bf, unsigned short* __restrict__ xkv_bf,
    unsigned short* __restrict__ wq_bf, unsigned short* __restrict__ wkv_bf,
    unsigned short* __restrict__ wp_bf, unsigned short* __restrict__ wo_bf,
    unsigned short* __restrict__ sc_bf) {
  int gid = blockIdx.x * 256 + threadIdx.x;
  if (gid < PREP_B) {            // cvt x_q / x_kv, float4 -> 4x bf16
    const float* src = (gid < PREP_A) ? x_q : x_kv;
    unsigned short* dst = (gid < PREP_A) ? xq_bf : xkv_bf;
    int e4 = (gid < PREP_A ? gid : gid - PREP_A) * 4;
    float4 v = *(const float4*)(src + e4);
    ushort4 o = { f2bf(v.x), f2bf(v.y), f2bf(v.z), f2bf(v.w) };
    *(ushort4*)(dst + e4) = o;
  } else if (gid < PREP_C) {     // pack4: (DHEAD,NH,DIM) -> (h*64+d, DIM)
    int e = gid - PREP_B;
    int which = e >> 18, inner = e & 262143;
    int e4 = inner * 4;
    int j = e4 >> 10, b = e4 & 1023;
    int d = j & 63, h = j >> 6;
    const float* w = (which == 0) ? to_q : (which == 1) ? to_k : (which == 2) ? to_v : to_pe;
    unsigned short* o = (which == 0) ? wq_bf : (which == 1) ? wkv_bf
                       : (which == 2) ? (wkv_bf + (size_t)DIM * DIM) : wp_bf;
    float4 v = *(const float4*)(w + (size_t)(d * NH + h) * DIM + b);
    ushort4 u = { f2bf(v.x), f2bf(v.y), f2bf(v.z), f2bf(v.w) };
    *(ushort4*)(o + e4) = u;
  } else if (gid < PREP_D) {     // pack_wo: (DIM,DHEAD,NH) -> (DIM, h*64+c)
    int e4 = (gid - PREP_C) * 4;
    int dd = e4 >> 10, jc = e4 & 1023;
    int c = jc & 63, h = jc >> 6;
    const float* base = to_out + (size_t)(dd * DHEAD + c) * NH + h;
    ushort4 u = { f2bf(base[0]), f2bf(base[16]), f2bf(base[32]), f2bf(base[48]) };
    *(ushort4*)(wo_bf + e4) = u;
  } else if (gid < PREP_E) {     // sincos: row r, 2 k2-cols per thread
    int e = gid - PREP_D;
    int r = e >> 8, t8 = e & 255;
    float ph0base = (float)(r - 63);
    unsigned short ss[2], cc[2];
    #pragma unroll
    for (int i = 0; i < 2; ++i) {
      int k2 = t8 * 2 + i;
      float invf = __expf((float)k2 * (-9.210340371976184f / 512.0f));  // 10000^(-k2/512)
      float s, c;
      __sincosf(ph0base * invf, &s, &c);
      ss[i] = f2bf(s); cc[i] = f2bf(c);
    }
    unsigned short* row = sc_bf + (size_t)r * DIM;
    *(unsigned int*)(row + t8 * 2)       = (unsigned)ss[0] | ((unsigned)ss[1] << 16);
    *(unsigned int*)(row + t8 * 2 + 512) = (unsigned)cc[0] | ((unsigned)cc[1] << 16);
  }
}

// ---------- fused input GEMMs, 128x64 tiles, 1040 blocks (R9 config: NO swizzle) ----------
__global__ __launch_bounds__(256) void gemm_in_kernel(
    const unsigned short* __restrict__ xq, const unsigned short* __restrict__ xkv,
    const unsigned short* __restrict__ sc,
    const unsigned short* __restrict__ wq, const unsigned short* __restrict__ wkv,
    const unsigned short* __restrict__ wp,
    unsigned short* __restrict__ qout, unsigned short* __restrict__ kout,
    unsigned short* __restrict__ vtout, unsigned short* __restrict__ peout) {
  int bid = (int)blockIdx.x;
  const unsigned short *A, *B; unsigned short *C1, *C2;
  int Mr, maxBrow, mode, ax, by;
  if (bid < 256)      { int t = bid;       ax = t & 15; by = t >> 4; A = xq;  B = wq;  C1 = qout;  C2 = nullptr; Mr = N_Q;    maxBrow = DIM - 1;     mode = 1; }
  else if (bid < 768) { int t = bid - 256; ax = t & 15; by = t >> 4; A = xkv; B = wkv; C1 = kout;  C2 = vtout;   Mr = M_KV;   maxBrow = 2 * DIM - 1; mode = 3; }
  else                { int t = bid - 768; ax = t % 17; by = t / 17; A = sc;  B = wp;  C1 = peout; C2 = nullptr; Mr = PEROWS; maxBrow = DIM - 1;     mode = 1; }

  __shared__ unsigned short As[2][128][64];
  __shared__ unsigned short Bs[2][64][64];
  int tid  = threadIdx.x;
  int wave = tid >> 6, lane = tid & 63;
  int g = lane >> 4, r16 = lane & 15;
  int arow0 = ax * 128;
  int brow0 = by * 64;
  int amax  = Mr - 1;

  auto stage = [&](int buf, int kt) {
    #pragma unroll
    for (int n = 0; n < 4; ++n) {
      int seg  = wave * 4 + n;
      int rloc = seg * 8 + (lane >> 3);
      int cbyte = ((lane & 7) << 4) ^ ((rloc & 7) << 4);
      int grow = min(arow0 + rloc, amax);
      const unsigned short* gp = A + (size_t)grow * KDIM + kt + (cbyte >> 1);
      __builtin_amdgcn_global_load_lds((gbyte_t*)(const void*)gp,
                                       (lbyte_t*)(void*)&As[buf][seg * 8][0], 16, 0, 0);
    }
    #pragma unroll
    for (int n = 0; n < 2; ++n) {
      int seg  = wave * 2 + n;
      int rloc = seg * 8 + (lane >> 3);
      int cbyte = ((lane & 7) << 4) ^ ((rloc & 7) << 4);
      int grow = min(brow0 + rloc, maxBrow);
      const unsigned short* gp = B + (size_t)grow * KDIM + kt + (cbyte >> 1);
      __builtin_amdgcn_global_load_lds((gbyte_t*)(const void*)gp,
                                       (lbyte_t*)(void*)&Bs[buf][seg * 8][0], 16, 0, 0);
    }
  };

  f32x4 acc[2][4];
  #pragma unroll
  for (int i = 0; i < 2; ++i)
    #pragma unroll
    for (int j = 0; j < 4; ++j) acc[i][j] = (f32x4){0,0,0,0};

  stage(0, 0);
  asm volatile("s_waitcnt vmcnt(0)" ::: "memory");
  __syncthreads();

  int buf = 0;
  for (int t = 0; t < 16; ++t) {
    if (t < 15) stage(buf ^ 1, (t + 1) * 64);

    bf16x8 af[2][2], bfr[4][2];
    #pragma unroll
    for (int i = 0; i < 2; ++i)
      #pragma unroll
      for (int kk = 0; kk < 2; ++kk) {
        int r = wave * 32 + i * 16 + r16;
        int cb = ((kk << 6) | (g << 4)) ^ ((r & 7) << 4);
        af[i][kk] = *(const bf16x8*)((const char*)&As[buf][r][0] + cb);
      }
    #pragma unroll
    for (int j = 0; j < 4; ++j)
      #pragma unroll
      for (int kk = 0; kk < 2; ++kk) {
        int r = j * 16 + r16;
        int cb = ((kk << 6) | (g << 4)) ^ ((r & 7) << 4);
        bfr[j][kk] = *(const bf16x8*)((const char*)&Bs[buf][r][0] + cb);
      }
    __builtin_amdgcn_s_setprio(1);
    #pragma unroll
    for (int kk = 0; kk < 2; ++kk)
      #pragma unroll
      for (int i = 0; i < 2; ++i)
        #pragma unroll
        for (int j = 0; j < 4; ++j)
          acc[i][j] = __builtin_amdgcn_mfma_f32_16x16x32_bf16(af[i][kk], bfr[j][kk], acc[i][j], 0, 0, 0);
    __builtin_amdgcn_s_setprio(0);

    if (t < 15) {
      asm volatile("s_waitcnt vmcnt(0)" ::: "memory");
      __syncthreads();
      buf ^= 1;
    }
  }

  #pragma unroll
  for (int i = 0; i < 2; ++i)
    #pragma unroll
    for (int j = 0; j < 4; ++j)
      #pragma unroll
      for (int rr = 0; rr < 4; ++rr) {
        int row = arow0 + wave * 32 + i * 16 + g * 4 + rr;
        int col = brow0 + j * 16 + r16;
        float v = acc[i][j][rr];
        if (mode == 1) {
          if (row < Mr) C1[(size_t)row * 1024 + col] = f2bf(v);
        } else {
          if (col < 1024) C1[(size_t)row * 1024 + col] = f2bf(v);
          else            C2[(size_t)(col - 1024) * M_KV + row] = f2bf(v);
        }
      }
}

// ---------- output projection GEMM: 128x64 tiles, grid(16,16), f32 out (R9 config) ----------
__global__ __launch_bounds__(256) void gemm_out_kernel(
    const unsigned short* __restrict__ A, const unsigned short* __restrict__ B,
    float* __restrict__ C1) {
  __shared__ unsigned short As[2][128][64];
  __shared__ unsigned short Bs[2][64][64];
  int tid  = threadIdx.x;
  int wave = tid >> 6, lane = tid & 63;
  int g = lane >> 4, r16 = lane & 15;
  int arow0 = blockIdx.x * 128;
  int brow0 = blockIdx.y * 64;

  auto stage = [&](int buf, int kt) {
    #pragma unroll
    for (int n = 0; n < 4; ++n) {
      int seg  = wave * 4 + n;
      int rloc = seg * 8 + (lane >> 3);
      int cbyte = ((lane & 7) << 4) ^ ((rloc & 7) << 4);
      const unsigned short* gp = A + (size_t)(arow0 + rloc) * KDIM + kt + (cbyte >> 1);
      __builtin_amdgcn_global_load_lds((gbyte_t*)(const void*)gp,
                                       (lbyte_t*)(void*)&As[buf][seg * 8][0], 16, 0, 0);
    }
    #pragma unroll
    for (int n = 0; n < 2; ++n) {
      int seg  = wave * 2 + n;
      int rloc = seg * 8 + (lane >> 3);
      int cbyte = ((lane & 7) << 4) ^ ((rloc & 7) << 4);
      const unsigned short* gp = B + (size_t)(brow0 + rloc) * KDIM + kt + (cbyte >> 1);
      __builtin_amdgcn_global_load_lds((gbyte_t*)(const void*)gp,
                                       (lbyte_t*)(void*)&Bs[buf][seg * 8][0], 16, 0, 0);
    }
  };

  f32x4 acc[2][4];
  #pragma unroll
  for (int i = 0; i < 2; ++i)
    #pragma unroll
    for (int j = 0; j < 4; ++j) acc[i][j] = (f32x4){0,0,0,0};

  stage(0, 0);
  asm volatile("s_waitcnt vmcnt(0)" ::: "memory");
  __syncthreads();

  int buf = 0;
  for (int t = 0; t < 16; ++t) {
    if (t < 15) stage(buf ^ 1, (t + 1) * 64);
    bf16x8 af[2][2], bfr[4][2];
    #pragma unroll
    for (int i = 0; i < 2; ++i)
      #pragma unroll
      for (int kk = 0; kk < 2; ++kk) {
        int r = wave * 32 + i * 16 + r16;
        int cb = ((kk << 6) | (g << 4)) ^ ((r & 7) << 4);
        af[i][kk] = *(const bf16x8*)((const char*)&As[buf][r][0] + cb);
      }
    #pragma unroll
    for (int j = 0; j < 4; ++j)
      #pragma unroll
      for (int kk = 0; kk < 2; ++kk) {
        int r = j * 16 + r16;
        int cb = ((kk << 6) | (g << 4)) ^ ((r & 7) << 4);
        bfr[j][kk] = *(const bf16x8*)((const char*)&Bs[buf][r][0] + cb);
      }
    __builtin_amdgcn_s_setprio(1);
    #pragma unroll
    for (int kk = 0; kk < 2; ++kk)
      #pragma unroll
      for (int i = 0; i < 2; ++i)
        #pragma unroll
        for (int j = 0; j < 4; ++j)
          acc[i][j] = __builtin_amdgcn_mfma_f32_16x16x32_bf16(af[i][kk], bfr[j][kk], acc[i][j], 0, 0, 0);
    __builtin_amdgcn_s_setprio(0);
    if (t < 15) {
      asm volatile("s_waitcnt vmcnt(0)" ::: "memory");
      __syncthreads();
      buf ^= 1;
    }
  }

  #pragma unroll
  for (int i = 0; i < 2; ++i)
    #pragma unroll
    for (int j = 0; j < 4; ++j)
      #pragma unroll
      for (int rr = 0; rr < 4; ++rr) {
        int row = arow0 + wave * 32 + i * 16 + g * 4 + rr;
        int col = brow0 + j * 16 + r16;
        C1[(size_t)row * 1024 + col] = acc[i][j][rr];
      }
}

// ---------- fused causal attention, MFMA, split-KV, T15 cross-tile pipeline ----------
// R9 skeleton (k/v/pe double-buffered in LDS, 2-phase, vmcnt(0)+barrier per tile),
// but the content+pos MFMA block for tile t+1 executes at the BOTTOM of iteration t
// (right after the barrier). The pos-MFMA -> shuffle-gather dependency then spans the
// entire stage+softmax+PV of the next iteration instead of stalling the gather.
__global__ __launch_bounds__(256, 2) void attn_mfma_kernel(
    const unsigned short* __restrict__ qb, const unsigned short* __restrict__ kb,
    const unsigned short* __restrict__ vt, const unsigned short* __restrict__ pe,
    unsigned short* __restrict__ ctx, float* __restrict__ part) {
  int ord  = (int)blockIdx.x;
  int h    = ord & 15;
  int widx = 79 - (ord >> 4);               // heavy chunks dispatched first
  int b, c;
  if (widx < 8)       { b = widx;                                  c = 0; }
  else if (widx < 24) { int t2 = widx - 8;  b = 8  + (t2 >> 1);    c = t2 & 1; }
  else if (widx < 48) { int t2 = widx - 24; int q3 = t2 / 3; b = 16 + q3; c = t2 - 3 * q3; }
  else                { int t2 = widx - 48; b = 24 + (t2 >> 2);    c = t2 & 3; }
  int n0   = b * 64;
  int nc   = (b < 8) ? 1 : (b >> 3) + 1;
  int t0   = c * 8;
  int tend = min(t0 + 8, b + 1);

  int wave = threadIdx.x >> 6;
  int lane = threadIdx.x & 63;
  int g    = lane >> 4;       // 0..3
  int r16  = lane & 15;       // 0..15

  __shared__ unsigned short Ks[2][64][64];     // 16 KB  k tile   [j-local][d]
  __shared__ unsigned short Vs[2][64][64];     // 16 KB  v tile   [d-local][j-local]
  __shared__ unsigned short PEs[2][128][64];   // 32 KB  pe band  [band-local][d]
  __shared__ unsigned short W_lds[4][16][72];  // 9.2 KB per-wave W

  const unsigned short* qrow = qb + (size_t)(n0 + wave * 16 + r16) * DIM + h * 64 + g * 8;
  bf16x8 aq0 = *(const bf16x8*)(qrow);
  bf16x8 aq1 = *(const bf16x8*)(qrow + 32);

  union { unsigned short u[8]; bf16x8 v; } one_u;
  #pragma unroll
  for (int i = 0; i < 8; ++i) one_u.u[i] = 0x3F80;   // bf16 1.0
  bf16x8 ones = one_u.v;

  f32x4 acc[4] = {{0,0,0,0},{0,0,0,0},{0,0,0,0},{0,0,0,0}};
  f32x4 lacc = {0,0,0,0};

  auto stage = [&](int bufn, int tilen) {
    int m0n = tilen * 64;
    int prb = n0 - m0n;
    #pragma unroll
    for (int n = 0; n < 2; ++n) {
      int seg  = wave * 2 + n;
      int rloc = seg * 8 + (lane >> 3);
      int cbyte = ((lane & 7) << 4) ^ ((rloc & 7) << 4);
      const unsigned short* gpk = kb + (size_t)(m0n + rloc) * KDIM + h * 64 + (cbyte >> 1);
      __builtin_amdgcn_global_load_lds((gbyte_t*)(const void*)gpk,
                                       (lbyte_t*)(void*)&Ks[bufn][seg * 8][0], 16, 0, 0);
      const unsigned short* gpv = vt + (size_t)(h * 64 + rloc) * M_KV + m0n + (cbyte >> 1);
      __builtin_amdgcn_global_load_lds((gbyte_t*)(const void*)gpv,
                                       (lbyte_t*)(void*)&Vs[bufn][seg * 8][0], 16, 0, 0);
    }
    #pragma unroll
    for (int n = 0; n < 4; ++n) {
      int seg  = wave * 4 + n;
      int rloc = seg * 8 + (lane >> 3);
      int cbyte = ((lane & 7) << 4) ^ ((rloc & 7) << 4);
      const unsigned short* gpp = pe + (size_t)(prb + rloc) * KDIM + h * 64 + (cbyte >> 1);
      __builtin_amdgcn_global_load_lds((gbyte_t*)(const void*)gpp,
                                       (lbyte_t*)(void*)&PEs[bufn][seg * 8][0], 16, 0, 0);
    }
  };

  int srcl[4]; bool hi_sel[4];
  #pragma unroll
  for (int rr = 0; rr < 4; ++rr) {
    srcl[rr]   = (g << 4) | ((g * 4 + rr + 63 - r16) & 15);
    hi_sel[rr] = (g * 4 + rr) > r16;
  }
  int sw = (r16 & 7) << 4;                     // read-side swizzle

  // cross-tile MFMA state (content sA, position zA) - computed one phase ahead
  f32x4 sA[4], zA[5];
  auto compute = [&](int bufc) {
    __builtin_amdgcn_s_setprio(1);
    #pragma unroll
    for (int ct = 0; ct < 4; ++ct) {
      const char* kbase = (const char*)&Ks[bufc][ct * 16 + r16][0];
      bf16x8 k0 = *(const bf16x8*)(kbase + (((g << 4)) ^ sw));
      bf16x8 k1 = *(const bf16x8*)(kbase + ((64 | (g << 4)) ^ sw));
      f32x4 z = {0,0,0,0};
      z = __builtin_amdgcn_mfma_f32_16x16x32_bf16(aq0, k0, z, 0, 0, 0);
      z = __builtin_amdgcn_mfma_f32_16x16x32_bf16(aq1, k1, z, 0, 0, 0);
      sA[ct] = z;
    }
    #pragma unroll
    for (int cp = 0; cp < 5; ++cp) {
      const char* pbase = (const char*)&PEs[bufc][wave * 16 + cp * 16 + r16][0];
      bf16x8 p0 = *(const bf16x8*)(pbase + (((g << 4)) ^ sw));
      bf16x8 p1 = *(const bf16x8*)(pbase + ((64 | (g << 4)) ^ sw));
      f32x4 z = {0,0,0,0};
      z = __builtin_amdgcn_mfma_f32_16x16x32_bf16(aq0, p0, z, 0, 0, 0);
      z = __builtin_amdgcn_mfma_f32_16x16x32_bf16(aq1, p1, z, 0, 0, 0);
      zA[cp] = z;
    }
    __builtin_amdgcn_s_setprio(0);
  };

  stage(0, t0);
  asm volatile("s_waitcnt vmcnt(0)" ::: "memory");
  __syncthreads();
  compute(0);                                  // tile t0's MFMAs

  int buf = 0;
  for (int tile = t0; tile < tend; ++tile) {
    int m0 = tile * 64;
    bool more = (tile + 1 < tend);
    if (more) stage(buf ^ 1, tile + 1);

    // ---- finish(tile): band gather (from zA) + causal mask + exp ----
    bool diag = (m0 == n0);
    f32x4 s[4];
    #pragma unroll
    for (int ct = 0; ct < 4; ++ct) {
      #pragma unroll
      for (int rr = 0; rr < 4; ++rr) {
        float vhi = __shfl(zA[4 - ct][rr], srcl[rr], 64);
        float vlo = __shfl(zA[3 - ct][rr], srcl[rr], 64);
        float p   = hi_sel[rr] ? vhi : vlo;
        int il = g * 4 + rr;
        int it = wave * 16 + il;
        int jt = ct * 16 + r16;
        float val = sA[ct][rr] + p;
        if (diag && jt > it) val = -1e30f;
        s[ct][rr] = __expf(val);
      }
    }

    // ---- W (bf16) to LDS, reread as PV A-fragments (wave-private) ----
    #pragma unroll
    for (int ct = 0; ct < 4; ++ct)
      #pragma unroll
      for (int rr = 0; rr < 4; ++rr)
        W_lds[wave][g * 4 + rr][ct * 16 + r16] = f2bf(s[ct][rr]);
    bf16x8 aw0 = *(const bf16x8*)(&W_lds[wave][r16][g * 8]);
    bf16x8 aw1 = *(const bf16x8*)(&W_lds[wave][r16][g * 8 + 32]);

    // ---- PV: 8 ds_read_b128 + 10 MFMA ----
    __builtin_amdgcn_s_setprio(1);
    #pragma unroll
    for (int ct = 0; ct < 4; ++ct) {
      const char* vbase = (const char*)&Vs[buf][ct * 16 + r16][0];
      bf16x8 v0 = *(const bf16x8*)(vbase + (((g << 4)) ^ sw));
      bf16x8 v1 = *(const bf16x8*)(vbase + ((64 | (g << 4)) ^ sw));
      f32x4 a = acc[ct];
      a = __builtin_amdgcn_mfma_f32_16x16x32_bf16(aw0, v0, a, 0, 0, 0);
      a = __builtin_amdgcn_mfma_f32_16x16x32_bf16(aw1, v1, a, 0, 0, 0);
      acc[ct] = a;
    }
    lacc = __builtin_amdgcn_mfma_f32_16x16x32_bf16(aw0, ones, lacc, 0, 0, 0);
    lacc = __builtin_amdgcn_mfma_f32_16x16x32_bf16(aw1, ones, lacc, 0, 0, 0);
    __builtin_amdgcn_s_setprio(0);

    // ---- bottom: drain stage, barrier, then compute(t+1) MFMAs from fresh buffer ----
    if (more) {
      asm volatile("s_waitcnt vmcnt(0)" ::: "memory");
      __builtin_amdgcn_s_barrier();
      __builtin_amdgcn_sched_barrier(0);
      compute(buf ^ 1);
      buf ^= 1;
    }
  }

  // ---- epilogue ----
  if (nc == 1) {
    #pragma unroll
    for (int rr = 0; rr < 4; ++rr) {
      float inv = 1.0f / lacc[rr];
      #pragma unroll
      for (int ct = 0; ct < 4; ++ct) {
        int row = n0 + wave * 16 + g * 4 + rr;
        ctx[(size_t)row * DIM + h * 64 + ct * 16 + r16] = f2bf(acc[ct][rr] * inv);
      }
    }
  } else {
    float* slot = part + ((size_t)((b - 8) * 16 + h) * 4 + c) * (64 * 68);
    #pragma unroll
    for (int ct = 0; ct < 4; ++ct)
      #pragma unroll
      for (int rr = 0; rr < 4; ++rr) {
        int row = wave * 16 + g * 4 + rr;
        slot[row * 68 + ct * 16 + r16] = acc[ct][rr];
      }
    if (r16 == 0) {
      #pragma unroll
      for (int rr = 0; rr < 4; ++rr) {
        int row = wave * 16 + g * 4 + rr;
        slot[row * 68 + 64] = lacc[rr];
      }
    }
  }
}

// ---------- merge split-KV partials (q-tiles b>=8) ----------
__global__ __launch_bounds__(256) void combine_kernel(const float* __restrict__ part,
                                                      unsigned short* __restrict__ ctx) {
  int bb = blockIdx.x;       // 0..23 -> b = bb+8
  int h  = blockIdx.y;
  int b  = bb + 8;
  int nc = (b >> 3) + 1;     // 2..4
  int t  = threadIdx.x;
  int row = t >> 2, q = t & 3;
  const float* base = part + ((size_t)(bb * 16 + h) * 4) * (64 * 68) + row * 68;
  float lstar = 0.0f;
  for (int c2 = 0; c2 < nc; ++c2) lstar += base[c2 * 4352 + 64];
  float inv = 1.0f / lstar;
  for (int cc = 0; cc < 16; ++cc) {
    int col = q * 16 + cc;
    float o = 0.0f;
    for (int c2 = 0; c2 < nc; ++c2) o += base[c2 * 4352 + col];
    ctx[(size_t)(b * 64 + row) * DIM + h * 64 + col] = f2bf(o * inv);
  }
}

extern "C" void kernel_launch(void* const* d_in, const int* in_sizes, int n_in,
                              void* d_out, int out_size, void* d_ws, size_t ws_size,
                              hipStream_t stream) {
  const float* x_q    = (const float*)d_in[0];
  const float* x_kv   = (const float*)d_in[1];
  const float* to_q   = (const float*)d_in[2];
  const float* to_k   = (const float*)d_in[3];
  const float* to_v   = (const float*)d_in[4];
  const float* to_out = (const float*)d_in[5];
  const float* to_pe  = (const float*)d_in[6];

  char* ws = (char*)d_ws;
  size_t off = 0;
  auto alloc = [&](size_t bytes) -> char* {
    char* p = ws + off;
    off += (bytes + 255) & ~(size_t)255;
    return p;
  };

  unsigned short* xq_bf  = (unsigned short*)alloc((size_t)N_Q  * DIM * 2);
  unsigned short* xkv_bf = (unsigned short*)alloc((size_t)M_KV * DIM * 2);
  unsigned short* wq_bf  = (unsigned short*)alloc((size_t)DIM * DIM * 2);
  unsigned short* wkv_bf = (unsigned short*)alloc((size_t)2 * DIM * DIM * 2);  // [wk; wv]
  unsigned short* wp_bf  = (unsigned short*)alloc((size_t)DIM * DIM * 2);
  unsigned short* wo_bf  = (unsigned short*)alloc((size_t)DIM * DIM * 2);
  unsigned short* sc_bf  = (unsigned short*)alloc((size_t)PEBUF * DIM * 2);
  unsigned short* q_bf   = (unsigned short*)alloc((size_t)N_Q  * DIM * 2);
  unsigned short* k_bf   = (unsigned short*)alloc((size_t)M_KV * DIM * 2);
  unsigned short* vt_bf  = (unsigned short*)alloc((size_t)DIM * M_KV * 2);
  unsigned short* pe_bf  = (unsigned short*)alloc((size_t)PEBUF * DIM * 2);
  unsigned short* ctx_bf = (unsigned short*)alloc((size_t)N_Q * DIM * 2);
  float*          part   = (float*)alloc((size_t)24 * 16 * 4 * 64 * 68 * 4);

  // fused prep (cvt + packs + sincos)
  prep_kernel<<<11392, 256, 0, stream>>>(x_q, x_kv, to_q, to_k, to_v, to_pe, to_out,
                                         xq_bf, xkv_bf, wq_bf, wkv_bf, wp_bf, wo_bf, sc_bf);

  // fused input projections (q, k|vt, pe), 128x64 tiles (R9 config, no swizzle)
  gemm_in_kernel<<<1040, 256, 0, stream>>>(xq_bf, xkv_bf, sc_bf, wq_bf, wkv_bf, wp_bf,
                                           q_bf, k_bf, vt_bf, pe_bf);

  // fused attention (split-KV, LDS 2-phase pipeline, T15 cross-tile compute) + combine
  attn_mfma_kernel<<<1280, 256, 0, stream>>>(q_bf, k_bf, vt_bf, pe_bf, ctx_bf, part);
  combine_kernel<<<dim3(24, NH), 256, 0, stream>>>(part, ctx_bf);

  // output projection -> d_out (f32)
  gemm_out_kernel<<<dim3(16, 16), 256, 0, stream>>>(ctx_bf, wo_bf, (float*)d_out);
}